// Round 5
// baseline (475.346 us; speedup 1.0000x reference)
//
#include <hip/hip_runtime.h>
#include <hip/hip_bf16.h>

typedef __attribute__((ext_vector_type(8))) __bf16 bf16x8;
typedef __attribute__((ext_vector_type(4))) float f32x4;

// ---------------- CSR build ----------------

__global__ void hist_kernel(const int* __restrict__ row, int* __restrict__ cnt, int e) {
  int i = blockIdx.x * 256 + threadIdx.x;
  if (i < e) atomicAdd(&cnt[row[i]], 1);
}

__global__ __launch_bounds__(1024) void scan_kernel(
    const int* __restrict__ cnt, int* __restrict__ off, int* __restrict__ cursor, int n, int e)
{
  __shared__ int sh[1024];
  const int tid = threadIdx.x;
  const int chunk = (n + 1023) >> 10;
  const int s0 = tid * chunk;
  const int s1 = (s0 + chunk < n) ? s0 + chunk : n;
  int sum = 0;
  for (int i = s0; i < s1; i++) sum += cnt[i];
  sh[tid] = sum;
  __syncthreads();
  for (int d = 1; d < 1024; d <<= 1) {
    int t = (tid >= d) ? sh[tid - d] : 0;
    __syncthreads();
    sh[tid] += t;
    __syncthreads();
  }
  int run = (tid > 0) ? sh[tid - 1] : 0;
  for (int i = s0; i < s1; i++) {
    int c = cnt[i];
    off[i] = run; cursor[i] = run; run += c;
  }
  if (tid == 0) off[n] = e;
}

__global__ void scatter_kernel(const int* __restrict__ row, const int* __restrict__ col,
                               int* __restrict__ cursor, int* __restrict__ scol, int e) {
  int i = blockIdx.x * 256 + threadIdx.x;
  if (i < e) { int r = row[i]; int pos = atomicAdd(&cursor[r], 1); scol[pos] = col[i]; }
}

// ---------------- W prep: Wt[c][k] = bf16(W[k][c]), c in [0,640) = q|kv|vec ----------------

__global__ void wprep_kernel(const float* __restrict__ Wq, const float* __restrict__ Wkv,
                             const float* __restrict__ Wvec, __bf16* __restrict__ Wt) {
  int idx = blockIdx.x * 256 + threadIdx.x;      // 640*128 = 81920
  int c = idx >> 7, k = idx & 127;
  float w;
  if (c < 128)      w = Wq[k * 128 + c];
  else if (c < 512) w = Wkv[k * 384 + (c - 128)];
  else              w = Wvec[k * 128 + (c - 512)];
  Wt[idx] = (__bf16)w;
}

// ---------------- GEMM1 (MFMA, fused cols): 64 rows x 512 cols per block ----------------
// chunk y: 0 -> q (f32), 1 -> k (bf16), 2 -> v_s (bf16), 3 -> P = v_v*v (bf16 x3)

__global__ __launch_bounds__(256) void gemm1_mfma(
    const float* __restrict__ s, const __bf16* __restrict__ Wtg,
    const float* __restrict__ bq, const float* __restrict__ bkv,
    const float* __restrict__ v,
    float* __restrict__ q_out, __bf16* __restrict__ nodebuf, int n)
{
  __shared__ __bf16 sA[64 * 136];
  __shared__ __bf16 sB[128 * 136];
  const int tid = threadIdx.x;
  const int n0 = blockIdx.x * 64;

  { // stage s tile -> bf16 LDS (coalesced float4 loads)
    int row = tid >> 2, seg = tid & 3;
    int gn = n0 + row;
    float4 f[8];
    if (gn < n) {
      #pragma unroll
      for (int i = 0; i < 8; i++)
        f[i] = *(const float4*)&s[(size_t)gn * 128 + seg * 32 + i * 4];
    } else {
      #pragma unroll
      for (int i = 0; i < 8; i++) f[i] = make_float4(0.f, 0.f, 0.f, 0.f);
    }
    #pragma unroll
    for (int i = 0; i < 4; i++) {
      bf16x8 pk;
      pk[0] = (__bf16)f[2*i].x;   pk[1] = (__bf16)f[2*i].y;
      pk[2] = (__bf16)f[2*i].z;   pk[3] = (__bf16)f[2*i].w;
      pk[4] = (__bf16)f[2*i+1].x; pk[5] = (__bf16)f[2*i+1].y;
      pk[6] = (__bf16)f[2*i+1].z; pk[7] = (__bf16)f[2*i+1].w;
      *(bf16x8*)&sA[row * 136 + seg * 32 + i * 8] = pk;
    }
  }

  const int wave = tid >> 6, lane = tid & 63;
  const int lr = lane & 15, lg = lane >> 4;
  bf16x8 a[4];

  #pragma unroll
  for (int y = 0; y < 4; y++) {
    { // stage W^T chunk y
      int row = tid >> 1, half = tid & 1;
      const __bf16* src = &Wtg[(size_t)(y * 128 + row) * 128 + half * 64];
      #pragma unroll
      for (int i = 0; i < 8; i++)
        *(bf16x8*)&sB[row * 136 + half * 64 + i * 8] = *(const bf16x8*)&src[i * 8];
    }
    __syncthreads();
    if (y == 0) {
      #pragma unroll
      for (int ks = 0; ks < 4; ks++)
        a[ks] = *(const bf16x8*)&sA[(wave * 16 + lr) * 136 + ks * 32 + lg * 8];
    }

    f32x4 acc[8];
    #pragma unroll
    for (int cf = 0; cf < 8; cf++) {
      f32x4 c = {0.f, 0.f, 0.f, 0.f};
      #pragma unroll
      for (int ks = 0; ks < 4; ks++) {
        bf16x8 b = *(const bf16x8*)&sB[(cf * 16 + lr) * 136 + ks * 32 + lg * 8];
        c = __builtin_amdgcn_mfma_f32_16x16x32_bf16(a[ks], b, c, 0, 0, 0);
      }
      acc[cf] = c;
    }

    // epilogue: D row = (lane>>4)*4 + r, col = lane&15
    #pragma unroll
    for (int cf = 0; cf < 8; cf++) {
      int cl = cf * 16 + lr;
      #pragma unroll
      for (int r = 0; r < 4; r++) {
        int gn = n0 + wave * 16 + lg * 4 + r;
        if (gn >= n) continue;
        float val = acc[cf][r];
        if (y == 0) {
          q_out[(size_t)gn * 128 + cl] = val + bq[cl];
        } else if (y == 1) {
          nodebuf[(size_t)gn * 640 + cl] = (__bf16)(val + bkv[cl]);
        } else if (y == 2) {
          nodebuf[(size_t)gn * 640 + 128 + cl] = (__bf16)(val + bkv[128 + cl]);
        } else {
          float vv = val + bkv[256 + cl];
          #pragma unroll
          for (int j3 = 0; j3 < 3; j3++) {
            float pv = vv * v[((size_t)gn * 3 + j3) * 128 + cl];
            nodebuf[(size_t)gn * 640 + 256 + j3 * 128 + cl] = (__bf16)pv;
          }
        }
      }
    }
    __syncthreads();
  }
}

// ---------------- Aggregation: one wave/node, 4 edges x 16 feature-lanes ----------------

__device__ inline float2 bf2f(unsigned u) {
  float2 r;
  r.x = __uint_as_float((u & 0xffffu) << 16);
  r.y = __uint_as_float(u & 0xffff0000u);
  return r;
}

#define ACC8(arr, vec) do { float2 _t;                                            \
  _t = bf2f(vec.x); arr[0] = fmaf(d, _t.x, arr[0]); arr[1] = fmaf(d, _t.y, arr[1]); \
  _t = bf2f(vec.y); arr[2] = fmaf(d, _t.x, arr[2]); arr[3] = fmaf(d, _t.y, arr[3]); \
  _t = bf2f(vec.z); arr[4] = fmaf(d, _t.x, arr[4]); arr[5] = fmaf(d, _t.y, arr[5]); \
  _t = bf2f(vec.w); arr[6] = fmaf(d, _t.x, arr[6]); arr[7] = fmaf(d, _t.y, arr[7]); \
} while (0)

__global__ __launch_bounds__(256) void agg_kernel(
    const int* __restrict__ off, const int* __restrict__ scol,
    const float* __restrict__ q, const char* __restrict__ nodebuf,
    const float* __restrict__ s, float* __restrict__ s_out, float* __restrict__ aggv, int n)
{
  const int wid = threadIdx.x >> 6;
  const int lane = threadIdx.x & 63;
  const int nid = blockIdx.x * 4 + wid;
  if (nid >= n) return;
  const int slot = lane >> 4;    // which of 4 concurrent edges
  const int fl = lane & 15;      // feature lane: dims [fl*8, fl*8+8)

  float qf[8];
  {
    float4 a = *(const float4*)&q[(size_t)nid * 128 + fl * 8];
    float4 b = *(const float4*)&q[(size_t)nid * 128 + fl * 8 + 4];
    qf[0] = a.x; qf[1] = a.y; qf[2] = a.z; qf[3] = a.w;
    qf[4] = b.x; qf[5] = b.y; qf[6] = b.z; qf[7] = b.w;
  }

  float acs[8], a0[8], a1[8], a2[8];
  #pragma unroll
  for (int i = 0; i < 8; i++) { acs[i] = 0.f; a0[i] = 0.f; a1[i] = 0.f; a2[i] = 0.f; }

  const int beg = off[nid];
  const int deg = off[nid + 1] - beg;

  for (int chunk = 0; chunk < deg; chunk += 64) {
    const int cc = (deg - chunk < 64) ? (deg - chunk) : 64;
    int myc = (lane < cc) ? scol[beg + chunk + lane] : 0;
    for (int j = 0; j < cc; j += 4) {
      const int idx = j + slot;
      int c = __shfl(myc, idx);
      const char* g = nodebuf + (size_t)c * 1280 + fl * 16;
      uint4 ku = *(const uint4*)(g);
      uint4 vs = *(const uint4*)(g + 256);
      uint4 p0 = *(const uint4*)(g + 512);
      uint4 p1 = *(const uint4*)(g + 768);
      uint4 p2 = *(const uint4*)(g + 1024);

      float2 t;
      float d = 0.f;
      t = bf2f(ku.x); d = fmaf(qf[0], t.x, d); d = fmaf(qf[1], t.y, d);
      t = bf2f(ku.y); d = fmaf(qf[2], t.x, d); d = fmaf(qf[3], t.y, d);
      t = bf2f(ku.z); d = fmaf(qf[4], t.x, d); d = fmaf(qf[5], t.y, d);
      t = bf2f(ku.w); d = fmaf(qf[6], t.x, d); d = fmaf(qf[7], t.y, d);
      // reduce within 16-lane group: 4 edges reduced simultaneously
      d += __shfl_xor(d, 1); d += __shfl_xor(d, 2);
      d += __shfl_xor(d, 4); d += __shfl_xor(d, 8);
      if (idx >= cc) d = 0.f;

      ACC8(acs, vs); ACC8(a0, p0); ACC8(a1, p1); ACC8(a2, p2);
    }
  }

  // cross-slot reduction (once per node)
  #pragma unroll
  for (int i = 0; i < 8; i++) {
    acs[i] += __shfl_xor(acs[i], 16); acs[i] += __shfl_xor(acs[i], 32);
    a0[i]  += __shfl_xor(a0[i], 16);  a0[i]  += __shfl_xor(a0[i], 32);
    a1[i]  += __shfl_xor(a1[i], 16);  a1[i]  += __shfl_xor(a1[i], 32);
    a2[i]  += __shfl_xor(a2[i], 16);  a2[i]  += __shfl_xor(a2[i], 32);
  }

  if (slot == 0) {
    const float* sp = &s[(size_t)nid * 128 + fl * 8];
    float4 w0, w1;
    w0.x = acs[0] + sp[0]; w0.y = acs[1] + sp[1]; w0.z = acs[2] + sp[2]; w0.w = acs[3] + sp[3];
    w1.x = acs[4] + sp[4]; w1.y = acs[5] + sp[5]; w1.z = acs[6] + sp[6]; w1.w = acs[7] + sp[7];
    *(float4*)&s_out[(size_t)nid * 128 + fl * 8] = w0;
    *(float4*)&s_out[(size_t)nid * 128 + fl * 8 + 4] = w1;

    float* av = &aggv[(size_t)nid * 384 + fl * 8];
    float4 u0, u1;
    u0.x = a0[0]; u0.y = a0[1]; u0.z = a0[2]; u0.w = a0[3];
    u1.x = a0[4]; u1.y = a0[5]; u1.z = a0[6]; u1.w = a0[7];
    *(float4*)&av[0] = u0; *(float4*)&av[4] = u1;
    u0.x = a1[0]; u0.y = a1[1]; u0.z = a1[2]; u0.w = a1[3];
    u1.x = a1[4]; u1.y = a1[5]; u1.z = a1[6]; u1.w = a1[7];
    *(float4*)&av[128] = u0; *(float4*)&av[132] = u1;
    u0.x = a2[0]; u0.y = a2[1]; u0.z = a2[2]; u0.w = a2[3];
    u1.x = a2[4]; u1.y = a2[5]; u1.z = a2[6]; u1.w = a2[7];
    *(float4*)&av[256] = u0; *(float4*)&av[260] = u1;
  }
}

// ---------------- GEMM2 (MFMA): vout = v + aggv @ Wvec + bvec, in-place on aggv rows ----------------

__global__ __launch_bounds__(256) void gemm2_mfma(
    const __bf16* __restrict__ Wtg,   // rows 512..639 = Wvec^T
    const float* __restrict__ bvec, const float* __restrict__ v,
    float* __restrict__ vout, int rows)
{
  __shared__ __bf16 sA[64 * 136];
  __shared__ __bf16 sB[128 * 136];
  const int tid = threadIdx.x;
  const int r0 = blockIdx.x * 64;

  { // stage A tile (f32 -> bf16, coalesced)
    int row = tid >> 2, seg = tid & 3;
    int gr = r0 + row;
    float4 f[8];
    if (gr < rows) {
      #pragma unroll
      for (int i = 0; i < 8; i++)
        f[i] = *(const float4*)&vout[(size_t)gr * 128 + seg * 32 + i * 4];
    } else {
      #pragma unroll
      for (int i = 0; i < 8; i++) f[i] = make_float4(0.f, 0.f, 0.f, 0.f);
    }
    #pragma unroll
    for (int i = 0; i < 4; i++) {
      bf16x8 pk;
      pk[0] = (__bf16)f[2*i].x;   pk[1] = (__bf16)f[2*i].y;
      pk[2] = (__bf16)f[2*i].z;   pk[3] = (__bf16)f[2*i].w;
      pk[4] = (__bf16)f[2*i+1].x; pk[5] = (__bf16)f[2*i+1].y;
      pk[6] = (__bf16)f[2*i+1].z; pk[7] = (__bf16)f[2*i+1].w;
      *(bf16x8*)&sA[row * 136 + seg * 32 + i * 8] = pk;
    }
  }
  { // stage Wvec^T
    int row = tid >> 1, half = tid & 1;
    const __bf16* src = &Wtg[(size_t)(512 + row) * 128 + half * 64];
    #pragma unroll
    for (int i = 0; i < 8; i++)
      *(bf16x8*)&sB[row * 136 + half * 64 + i * 8] = *(const bf16x8*)&src[i * 8];
  }
  __syncthreads();

  const int wave = tid >> 6, lane = tid & 63;
  const int lr = lane & 15, lg = lane >> 4;

  bf16x8 a[4];
  #pragma unroll
  for (int ks = 0; ks < 4; ks++)
    a[ks] = *(const bf16x8*)&sA[(wave * 16 + lr) * 136 + ks * 32 + lg * 8];

  f32x4 acc[8];
  #pragma unroll
  for (int cf = 0; cf < 8; cf++) {
    f32x4 c = {0.f, 0.f, 0.f, 0.f};
    #pragma unroll
    for (int ks = 0; ks < 4; ks++) {
      bf16x8 b = *(const bf16x8*)&sB[(cf * 16 + lr) * 136 + ks * 32 + lg * 8];
      c = __builtin_amdgcn_mfma_f32_16x16x32_bf16(a[ks], b, c, 0, 0, 0);
    }
    acc[cf] = c;
  }

  #pragma unroll
  for (int cf = 0; cf < 8; cf++) {
    int cl = cf * 16 + lr;
    #pragma unroll
    for (int r = 0; r < 4; r++) {
      int gr = r0 + wave * 16 + lg * 4 + r;
      if (gr >= rows) continue;
      vout[(size_t)gr * 128 + cl] = acc[cf][r] + v[(size_t)gr * 128 + cl] + bvec[cl];
    }
  }
}

// ---------------- launch ----------------

extern "C" void kernel_launch(void* const* d_in, const int* in_sizes, int n_in,
                              void* d_out, int out_size, void* d_ws, size_t ws_size,
                              hipStream_t stream)
{
  const float* s    = (const float*)d_in[0];
  const float* v    = (const float*)d_in[1];
  const int*   ei   = (const int*)d_in[2];
  const float* Wq   = (const float*)d_in[3];
  const float* bq   = (const float*)d_in[4];
  const float* Wkv  = (const float*)d_in[5];
  const float* bkv  = (const float*)d_in[6];
  const float* Wvec = (const float*)d_in[7];
  const float* bvec = (const float*)d_in[8];

  const int N = in_sizes[0] / 128;
  const int E = in_sizes[2] / 2;
  const int* row = ei;
  const int* col = ei + E;

  char* ws = (char*)d_ws;
  size_t o = 0;
  auto alloc = [&](size_t bytes) -> char* {
    char* p = ws + o;
    o = (o + bytes + 255) & ~(size_t)255;
    return p;
  };
  int* off    = (int*)alloc((size_t)(N + 1) * 4);
  int* cursor = (int*)alloc((size_t)N * 4);       // doubles as histogram counts
  int* scol   = (int*)alloc((size_t)E * 4);
  float* qbuf = (float*)alloc((size_t)N * 128 * 4);
  __bf16* nodebuf = (__bf16*)alloc((size_t)N * 640 * 2);
  __bf16* Wt  = (__bf16*)alloc((size_t)640 * 128 * 2);

  float* s_out = (float*)d_out;
  float* aggv  = (float*)d_out + (size_t)N * 128;

  // CSR build
  hipMemsetAsync(cursor, 0, (size_t)N * 4, stream);
  hist_kernel<<<(E + 255) / 256, 256, 0, stream>>>(row, cursor, E);
  scan_kernel<<<1, 1024, 0, stream>>>(cursor, off, cursor, N, E);
  scatter_kernel<<<(E + 255) / 256, 256, 0, stream>>>(row, col, cursor, scol, E);

  // weight prep + node features (MFMA, fused col chunks)
  wprep_kernel<<<320, 256, 0, stream>>>(Wq, Wkv, Wvec, Wt);
  gemm1_mfma<<<(N + 63) / 64, 256, 0, stream>>>(s, Wt, bq, bkv, v, qbuf, nodebuf, N);

  // edge aggregation (one wave per node, 4 edges x 16 lanes)
  agg_kernel<<<(N + 3) / 4, 256, 0, stream>>>(off, scol, qbuf, (const char*)nodebuf,
                                              s, s_out, aggv, N);

  // v_out GEMM (MFMA, in-place on d_out v region)
  gemm2_mfma<<<(3 * N + 63) / 64, 256, 0, stream>>>(Wt, bvec, v, aggv, 3 * N);
}

// Round 6
// 438.003 us; speedup vs baseline: 1.0853x; 1.0853x over previous
//
#include <hip/hip_runtime.h>
#include <hip/hip_bf16.h>

typedef __attribute__((ext_vector_type(8))) __bf16 bf16x8;
typedef __attribute__((ext_vector_type(4))) float f32x4;

// ---------------- CSR build ----------------

__global__ void hist_kernel(const int* __restrict__ row, int* __restrict__ cnt, int e) {
  int i = blockIdx.x * 256 + threadIdx.x;
  if (i < e) atomicAdd(&cnt[row[i]], 1);
}

__global__ __launch_bounds__(1024) void scan_kernel(
    const int* __restrict__ cnt, int* __restrict__ off, int* __restrict__ cursor, int n, int e)
{
  __shared__ int sh[1024];
  const int tid = threadIdx.x;
  const int chunk = (n + 1023) >> 10;
  const int s0 = tid * chunk;
  const int s1 = (s0 + chunk < n) ? s0 + chunk : n;
  int sum = 0;
  for (int i = s0; i < s1; i++) sum += cnt[i];
  sh[tid] = sum;
  __syncthreads();
  for (int d = 1; d < 1024; d <<= 1) {
    int t = (tid >= d) ? sh[tid - d] : 0;
    __syncthreads();
    sh[tid] += t;
    __syncthreads();
  }
  int run = (tid > 0) ? sh[tid - 1] : 0;
  for (int i = s0; i < s1; i++) {
    int c = cnt[i];
    off[i] = run; cursor[i] = run; run += c;
  }
  if (tid == 0) off[n] = e;
}

__global__ void scatter_kernel(const int* __restrict__ row, const int* __restrict__ col,
                               int* __restrict__ cursor, int* __restrict__ scol, int e) {
  int i = blockIdx.x * 256 + threadIdx.x;
  if (i < e) { int r = row[i]; int pos = atomicAdd(&cursor[r], 1); scol[pos] = col[i]; }
}

// ---------------- W prep: Wt[c][k] = bf16(W[k][c]), c in [0,640) = q|kv|vec ----------------

__global__ void wprep_kernel(const float* __restrict__ Wq, const float* __restrict__ Wkv,
                             const float* __restrict__ Wvec, __bf16* __restrict__ Wt) {
  int idx = blockIdx.x * 256 + threadIdx.x;      // 640*128 = 81920
  int c = idx >> 7, k = idx & 127;
  float w;
  if (c < 128)      w = Wq[k * 128 + c];
  else if (c < 512) w = Wkv[k * 384 + (c - 128)];
  else              w = Wvec[k * 128 + (c - 512)];
  Wt[idx] = (__bf16)w;
}

// ---------------- GEMM1 (MFMA, fused cols, LDS-staged coalesced output) ----------------
// chunk y: 0 -> q (f32), 1 -> k (bf16), 2 -> v_s (bf16), 3 -> P = v_v*v (bf16 x3)

__global__ __launch_bounds__(256) void gemm1_mfma(
    const float* __restrict__ s, const __bf16* __restrict__ Wtg,
    const float* __restrict__ bq, const float* __restrict__ bkv,
    const float* __restrict__ v,
    float* __restrict__ q_out, __bf16* __restrict__ nodebuf, int n)
{
  __shared__ __bf16 sA[64 * 136];
  __shared__ char uB[34816];                 // union: sB (bf16 [128][136]) / sO (f32 [64][132])
  __bf16* sB = (__bf16*)uB;
  float*  sO = (float*)uB;

  const int tid = threadIdx.x;
  const int n0 = blockIdx.x * 64;
  const int drow = tid >> 2, dseg = tid & 3;     // drain mapping
  const int dgn = n0 + drow;

  { // stage s tile -> bf16 LDS (coalesced float4 loads)
    float4 f[8];
    if (dgn < n) {
      #pragma unroll
      for (int i = 0; i < 8; i++)
        f[i] = *(const float4*)&s[(size_t)dgn * 128 + dseg * 32 + i * 4];
    } else {
      #pragma unroll
      for (int i = 0; i < 8; i++) f[i] = make_float4(0.f, 0.f, 0.f, 0.f);
    }
    #pragma unroll
    for (int i = 0; i < 4; i++) {
      bf16x8 pk;
      pk[0] = (__bf16)f[2*i].x;   pk[1] = (__bf16)f[2*i].y;
      pk[2] = (__bf16)f[2*i].z;   pk[3] = (__bf16)f[2*i].w;
      pk[4] = (__bf16)f[2*i+1].x; pk[5] = (__bf16)f[2*i+1].y;
      pk[6] = (__bf16)f[2*i+1].z; pk[7] = (__bf16)f[2*i+1].w;
      *(bf16x8*)&sA[drow * 136 + dseg * 32 + i * 8] = pk;
    }
  }

  const int wave = tid >> 6, lane = tid & 63;
  const int lr = lane & 15, lg = lane >> 4;
  bf16x8 a[4];
  bool afrag_loaded = false;

  #pragma unroll
  for (int y = 0; y < 4; y++) {
    { // stage W^T chunk y
      int row = tid >> 1, half = tid & 1;
      const __bf16* src = &Wtg[(size_t)(y * 128 + row) * 128 + half * 64];
      #pragma unroll
      for (int i = 0; i < 8; i++)
        *(bf16x8*)&sB[row * 136 + half * 64 + i * 8] = *(const bf16x8*)&src[i * 8];
    }
    __syncthreads();
    if (!afrag_loaded) {
      #pragma unroll
      for (int ks = 0; ks < 4; ks++)
        a[ks] = *(const bf16x8*)&sA[(wave * 16 + lr) * 136 + ks * 32 + lg * 8];
      afrag_loaded = true;
    }

    f32x4 acc[8];
    #pragma unroll
    for (int cf = 0; cf < 8; cf++) {
      f32x4 c = {0.f, 0.f, 0.f, 0.f};
      #pragma unroll
      for (int ks = 0; ks < 4; ks++) {
        bf16x8 b = *(const bf16x8*)&sB[(cf * 16 + lr) * 136 + ks * 32 + lg * 8];
        c = __builtin_amdgcn_mfma_f32_16x16x32_bf16(a[ks], b, c, 0, 0, 0);
      }
      acc[cf] = c;
    }
    __syncthreads();   // all waves done reading sB; safe to overwrite with sO

    // write acc -> sO[row][col], row = wave*16 + lg*4 + r, col = cf*16 + lr
    #pragma unroll
    for (int cf = 0; cf < 8; cf++) {
      int cl = cf * 16 + lr;
      #pragma unroll
      for (int r = 0; r < 4; r++)
        sO[(wave * 16 + lg * 4 + r) * 132 + cl] = acc[cf][r];
    }
    __syncthreads();

    // drain: coalesced wide global I/O
    if (dgn < n) {
      if (y == 0) {
        #pragma unroll
        for (int i = 0; i < 8; i++) {
          int c0 = dseg * 32 + i * 4;
          float4 o;
          o.x = sO[drow * 132 + c0 + 0] + bq[c0 + 0];
          o.y = sO[drow * 132 + c0 + 1] + bq[c0 + 1];
          o.z = sO[drow * 132 + c0 + 2] + bq[c0 + 2];
          o.w = sO[drow * 132 + c0 + 3] + bq[c0 + 3];
          *(float4*)&q_out[(size_t)dgn * 128 + c0] = o;
        }
      } else if (y == 1 || y == 2) {
        const int boff = (y - 1) * 128;
        #pragma unroll
        for (int i = 0; i < 4; i++) {
          int c0 = dseg * 32 + i * 8;
          bf16x8 pk;
          #pragma unroll
          for (int j = 0; j < 8; j++)
            pk[j] = (__bf16)(sO[drow * 132 + c0 + j] + bkv[boff + c0 + j]);
          *(bf16x8*)&nodebuf[(size_t)dgn * 640 + boff + c0] = pk;
        }
      } else {
        float vv[32];
        #pragma unroll
        for (int j = 0; j < 32; j++)
          vv[j] = sO[drow * 132 + dseg * 32 + j] + bkv[256 + dseg * 32 + j];
        #pragma unroll
        for (int j3 = 0; j3 < 3; j3++) {
          #pragma unroll
          for (int i = 0; i < 4; i++) {
            int c0 = dseg * 32 + i * 8;
            float4 va = *(const float4*)&v[((size_t)dgn * 3 + j3) * 128 + c0];
            float4 vb = *(const float4*)&v[((size_t)dgn * 3 + j3) * 128 + c0 + 4];
            bf16x8 pk;
            pk[0] = (__bf16)(vv[i*8+0] * va.x); pk[1] = (__bf16)(vv[i*8+1] * va.y);
            pk[2] = (__bf16)(vv[i*8+2] * va.z); pk[3] = (__bf16)(vv[i*8+3] * va.w);
            pk[4] = (__bf16)(vv[i*8+4] * vb.x); pk[5] = (__bf16)(vv[i*8+5] * vb.y);
            pk[6] = (__bf16)(vv[i*8+6] * vb.z); pk[7] = (__bf16)(vv[i*8+7] * vb.w);
            *(bf16x8*)&nodebuf[(size_t)dgn * 640 + 256 + j3 * 128 + c0] = pk;
          }
        }
      }
    }
    __syncthreads();   // drain done before next sB restage
  }
}

// ---------------- Aggregation: one wave/node, 4 edges x 16 feature-lanes ----------------

__device__ inline float2 bf2f(unsigned u) {
  float2 r;
  r.x = __uint_as_float((u & 0xffffu) << 16);
  r.y = __uint_as_float(u & 0xffff0000u);
  return r;
}

#define ACC8(arr, vec) do { float2 _t;                                            \
  _t = bf2f(vec.x); arr[0] = fmaf(d, _t.x, arr[0]); arr[1] = fmaf(d, _t.y, arr[1]); \
  _t = bf2f(vec.y); arr[2] = fmaf(d, _t.x, arr[2]); arr[3] = fmaf(d, _t.y, arr[3]); \
  _t = bf2f(vec.z); arr[4] = fmaf(d, _t.x, arr[4]); arr[5] = fmaf(d, _t.y, arr[5]); \
  _t = bf2f(vec.w); arr[6] = fmaf(d, _t.x, arr[6]); arr[7] = fmaf(d, _t.y, arr[7]); \
} while (0)

__global__ __launch_bounds__(256) void agg_kernel(
    const int* __restrict__ off, const int* __restrict__ scol,
    const float* __restrict__ q, const char* __restrict__ nodebuf,
    const float* __restrict__ s, float* __restrict__ s_out, float* __restrict__ aggv, int n)
{
  const int wid = threadIdx.x >> 6;
  const int lane = threadIdx.x & 63;
  const int nid = blockIdx.x * 4 + wid;
  if (nid >= n) return;
  const int slot = lane >> 4;    // which of 4 concurrent edges
  const int fl = lane & 15;      // feature lane: dims [fl*8, fl*8+8)

  float qf[8];
  {
    float4 a = *(const float4*)&q[(size_t)nid * 128 + fl * 8];
    float4 b = *(const float4*)&q[(size_t)nid * 128 + fl * 8 + 4];
    qf[0] = a.x; qf[1] = a.y; qf[2] = a.z; qf[3] = a.w;
    qf[4] = b.x; qf[5] = b.y; qf[6] = b.z; qf[7] = b.w;
  }

  float acs[8], a0[8], a1[8], a2[8];
  #pragma unroll
  for (int i = 0; i < 8; i++) { acs[i] = 0.f; a0[i] = 0.f; a1[i] = 0.f; a2[i] = 0.f; }

  const int beg = off[nid];
  const int deg = off[nid + 1] - beg;

  for (int chunk = 0; chunk < deg; chunk += 64) {
    const int cc = (deg - chunk < 64) ? (deg - chunk) : 64;
    int myc = (lane < cc) ? scol[beg + chunk + lane] : 0;
    for (int j = 0; j < cc; j += 4) {
      const int idx = j + slot;
      int c = __shfl(myc, idx);
      const char* g = nodebuf + (size_t)c * 1280 + fl * 16;
      uint4 ku = *(const uint4*)(g);
      uint4 vs = *(const uint4*)(g + 256);
      uint4 p0 = *(const uint4*)(g + 512);
      uint4 p1 = *(const uint4*)(g + 768);
      uint4 p2 = *(const uint4*)(g + 1024);

      float2 t;
      float d = 0.f;
      t = bf2f(ku.x); d = fmaf(qf[0], t.x, d); d = fmaf(qf[1], t.y, d);
      t = bf2f(ku.y); d = fmaf(qf[2], t.x, d); d = fmaf(qf[3], t.y, d);
      t = bf2f(ku.z); d = fmaf(qf[4], t.x, d); d = fmaf(qf[5], t.y, d);
      t = bf2f(ku.w); d = fmaf(qf[6], t.x, d); d = fmaf(qf[7], t.y, d);
      d += __shfl_xor(d, 1); d += __shfl_xor(d, 2);
      d += __shfl_xor(d, 4); d += __shfl_xor(d, 8);
      if (idx >= cc) d = 0.f;

      ACC8(acs, vs); ACC8(a0, p0); ACC8(a1, p1); ACC8(a2, p2);
    }
  }

  #pragma unroll
  for (int i = 0; i < 8; i++) {
    acs[i] += __shfl_xor(acs[i], 16); acs[i] += __shfl_xor(acs[i], 32);
    a0[i]  += __shfl_xor(a0[i], 16);  a0[i]  += __shfl_xor(a0[i], 32);
    a1[i]  += __shfl_xor(a1[i], 16);  a1[i]  += __shfl_xor(a1[i], 32);
    a2[i]  += __shfl_xor(a2[i], 16);  a2[i]  += __shfl_xor(a2[i], 32);
  }

  if (slot == 0) {
    const float* sp = &s[(size_t)nid * 128 + fl * 8];
    float4 w0, w1;
    w0.x = acs[0] + sp[0]; w0.y = acs[1] + sp[1]; w0.z = acs[2] + sp[2]; w0.w = acs[3] + sp[3];
    w1.x = acs[4] + sp[4]; w1.y = acs[5] + sp[5]; w1.z = acs[6] + sp[6]; w1.w = acs[7] + sp[7];
    *(float4*)&s_out[(size_t)nid * 128 + fl * 8] = w0;
    *(float4*)&s_out[(size_t)nid * 128 + fl * 8 + 4] = w1;

    float* av = &aggv[(size_t)nid * 384 + fl * 8];
    float4 u0, u1;
    u0.x = a0[0]; u0.y = a0[1]; u0.z = a0[2]; u0.w = a0[3];
    u1.x = a0[4]; u1.y = a0[5]; u1.z = a0[6]; u1.w = a0[7];
    *(float4*)&av[0] = u0; *(float4*)&av[4] = u1;
    u0.x = a1[0]; u0.y = a1[1]; u0.z = a1[2]; u0.w = a1[3];
    u1.x = a1[4]; u1.y = a1[5]; u1.z = a1[6]; u1.w = a1[7];
    *(float4*)&av[128] = u0; *(float4*)&av[132] = u1;
    u0.x = a2[0]; u0.y = a2[1]; u0.z = a2[2]; u0.w = a2[3];
    u1.x = a2[4]; u1.y = a2[5]; u1.z = a2[6]; u1.w = a2[7];
    *(float4*)&av[256] = u0; *(float4*)&av[260] = u1;
  }
}

// ---------------- GEMM2 (MFMA, LDS-staged coalesced output): vout = v + aggv @ Wvec + bvec ----------------

__global__ __launch_bounds__(256) void gemm2_mfma(
    const __bf16* __restrict__ Wtg,   // rows 512..639 = Wvec^T
    const float* __restrict__ bvec, const float* __restrict__ v,
    float* __restrict__ vout, int rows)
{
  __shared__ __bf16 sA[64 * 136];
  __shared__ char uB[34816];
  __bf16* sB = (__bf16*)uB;
  float*  sO = (float*)uB;

  const int tid = threadIdx.x;
  const int r0 = blockIdx.x * 64;
  const int drow = tid >> 2, dseg = tid & 3;
  const int dgr = r0 + drow;

  { // stage A tile (f32 -> bf16, coalesced)
    float4 f[8];
    if (dgr < rows) {
      #pragma unroll
      for (int i = 0; i < 8; i++)
        f[i] = *(const float4*)&vout[(size_t)dgr * 128 + dseg * 32 + i * 4];
    } else {
      #pragma unroll
      for (int i = 0; i < 8; i++) f[i] = make_float4(0.f, 0.f, 0.f, 0.f);
    }
    #pragma unroll
    for (int i = 0; i < 4; i++) {
      bf16x8 pk;
      pk[0] = (__bf16)f[2*i].x;   pk[1] = (__bf16)f[2*i].y;
      pk[2] = (__bf16)f[2*i].z;   pk[3] = (__bf16)f[2*i].w;
      pk[4] = (__bf16)f[2*i+1].x; pk[5] = (__bf16)f[2*i+1].y;
      pk[6] = (__bf16)f[2*i+1].z; pk[7] = (__bf16)f[2*i+1].w;
      *(bf16x8*)&sA[drow * 136 + dseg * 32 + i * 8] = pk;
    }
  }
  { // stage Wvec^T
    int row = tid >> 1, half = tid & 1;
    const __bf16* src = &Wtg[(size_t)(512 + row) * 128 + half * 64];
    #pragma unroll
    for (int i = 0; i < 8; i++)
      *(bf16x8*)&sB[row * 136 + half * 64 + i * 8] = *(const bf16x8*)&src[i * 8];
  }
  __syncthreads();

  const int wave = tid >> 6, lane = tid & 63;
  const int lr = lane & 15, lg = lane >> 4;

  bf16x8 a[4];
  #pragma unroll
  for (int ks = 0; ks < 4; ks++)
    a[ks] = *(const bf16x8*)&sA[(wave * 16 + lr) * 136 + ks * 32 + lg * 8];

  f32x4 acc[8];
  #pragma unroll
  for (int cf = 0; cf < 8; cf++) {
    f32x4 c = {0.f, 0.f, 0.f, 0.f};
    #pragma unroll
    for (int ks = 0; ks < 4; ks++) {
      bf16x8 b = *(const bf16x8*)&sB[(cf * 16 + lr) * 136 + ks * 32 + lg * 8];
      c = __builtin_amdgcn_mfma_f32_16x16x32_bf16(a[ks], b, c, 0, 0, 0);
    }
    acc[cf] = c;
  }
  __syncthreads();   // done reading sB

  #pragma unroll
  for (int cf = 0; cf < 8; cf++) {
    int cl = cf * 16 + lr;
    #pragma unroll
    for (int r = 0; r < 4; r++)
      sO[(wave * 16 + lg * 4 + r) * 132 + cl] = acc[cf][r];
  }
  __syncthreads();

  if (dgr < rows) {
    #pragma unroll
    for (int i = 0; i < 8; i++) {
      int c0 = dseg * 32 + i * 4;
      float4 va = *(const float4*)&v[(size_t)dgr * 128 + c0];
      float4 o;
      o.x = sO[drow * 132 + c0 + 0] + va.x + bvec[c0 + 0];
      o.y = sO[drow * 132 + c0 + 1] + va.y + bvec[c0 + 1];
      o.z = sO[drow * 132 + c0 + 2] + va.z + bvec[c0 + 2];
      o.w = sO[drow * 132 + c0 + 3] + va.w + bvec[c0 + 3];
      *(float4*)&vout[(size_t)dgr * 128 + c0] = o;
    }
  }
}

// ---------------- launch ----------------

extern "C" void kernel_launch(void* const* d_in, const int* in_sizes, int n_in,
                              void* d_out, int out_size, void* d_ws, size_t ws_size,
                              hipStream_t stream)
{
  const float* s    = (const float*)d_in[0];
  const float* v    = (const float*)d_in[1];
  const int*   ei   = (const int*)d_in[2];
  const float* Wq   = (const float*)d_in[3];
  const float* bq   = (const float*)d_in[4];
  const float* Wkv  = (const float*)d_in[5];
  const float* bkv  = (const float*)d_in[6];
  const float* Wvec = (const float*)d_in[7];
  const float* bvec = (const float*)d_in[8];

  const int N = in_sizes[0] / 128;
  const int E = in_sizes[2] / 2;
  const int* row = ei;
  const int* col = ei + E;

  char* ws = (char*)d_ws;
  size_t o = 0;
  auto alloc = [&](size_t bytes) -> char* {
    char* p = ws + o;
    o = (o + bytes + 255) & ~(size_t)255;
    return p;
  };
  int* off    = (int*)alloc((size_t)(N + 1) * 4);
  int* cursor = (int*)alloc((size_t)N * 4);       // doubles as histogram counts
  int* scol   = (int*)alloc((size_t)E * 4);
  float* qbuf = (float*)alloc((size_t)N * 128 * 4);
  __bf16* nodebuf = (__bf16*)alloc((size_t)N * 640 * 2);
  __bf16* Wt  = (__bf16*)alloc((size_t)640 * 128 * 2);

  float* s_out = (float*)d_out;
  float* aggv  = (float*)d_out + (size_t)N * 128;

  // CSR build
  hipMemsetAsync(cursor, 0, (size_t)N * 4, stream);
  hist_kernel<<<(E + 255) / 256, 256, 0, stream>>>(row, cursor, E);
  scan_kernel<<<1, 1024, 0, stream>>>(cursor, off, cursor, N, E);
  scatter_kernel<<<(E + 255) / 256, 256, 0, stream>>>(row, col, cursor, scol, E);

  // weight prep + node features (MFMA, fused col chunks, coalesced epilogue)
  wprep_kernel<<<320, 256, 0, stream>>>(Wq, Wkv, Wvec, Wt);
  gemm1_mfma<<<(N + 63) / 64, 256, 0, stream>>>(s, Wt, bq, bkv, v, qbuf, nodebuf, N);

  // edge aggregation (one wave per node, 4 edges x 16 lanes)
  agg_kernel<<<(N + 3) / 4, 256, 0, stream>>>(off, scol, qbuf, (const char*)nodebuf,
                                              s, s_out, aggv, N);

  // v_out GEMM (MFMA, in-place on d_out v region, coalesced epilogue)
  gemm2_mfma<<<(3 * N + 63) / 64, 256, 0, stream>>>(Wt, bvec, v, aggv, 3 * N);
}

// Round 7
// 416.505 us; speedup vs baseline: 1.1413x; 1.0516x over previous
//
#include <hip/hip_runtime.h>
#include <hip/hip_bf16.h>

typedef __attribute__((ext_vector_type(8))) __bf16 bf16x8;
typedef __attribute__((ext_vector_type(4))) float f32x4;

// ---------------- CSR build ----------------

__global__ void hist_kernel(const int* __restrict__ row, int* __restrict__ cnt, int e) {
  int i = blockIdx.x * 256 + threadIdx.x;
  if (i < e) atomicAdd(&cnt[row[i]], 1);
}

__global__ __launch_bounds__(1024) void scan_kernel(
    const int* __restrict__ cnt, int* __restrict__ off, int* __restrict__ cursor, int n, int e)
{
  __shared__ int sh[1024];
  const int tid = threadIdx.x;
  const int chunk = (n + 1023) >> 10;
  const int s0 = tid * chunk;
  const int s1 = (s0 + chunk < n) ? s0 + chunk : n;
  int sum = 0;
  for (int i = s0; i < s1; i++) sum += cnt[i];
  sh[tid] = sum;
  __syncthreads();
  for (int d = 1; d < 1024; d <<= 1) {
    int t = (tid >= d) ? sh[tid - d] : 0;
    __syncthreads();
    sh[tid] += t;
    __syncthreads();
  }
  int run = (tid > 0) ? sh[tid - 1] : 0;
  for (int i = s0; i < s1; i++) {
    int c = cnt[i];
    off[i] = run; cursor[i] = run; run += c;
  }
  if (tid == 0) off[n] = e;
}

__global__ void scatter_kernel(const int* __restrict__ row, const int* __restrict__ col,
                               int* __restrict__ cursor, int* __restrict__ scol, int e) {
  int i = blockIdx.x * 256 + threadIdx.x;
  if (i < e) { int r = row[i]; int pos = atomicAdd(&cursor[r], 1); scol[pos] = col[i]; }
}

// ---------------- W prep: Wt[c][k] = bf16(W[k][c]), c in [0,640) = q|kv|vec ----------------

__global__ void wprep_kernel(const float* __restrict__ Wq, const float* __restrict__ Wkv,
                             const float* __restrict__ Wvec, __bf16* __restrict__ Wt) {
  int idx = blockIdx.x * 256 + threadIdx.x;      // 640*128 = 81920
  int c = idx >> 7, k = idx & 127;
  float w;
  if (c < 128)      w = Wq[k * 128 + c];
  else if (c < 512) w = Wkv[k * 384 + (c - 128)];
  else              w = Wvec[k * 128 + (c - 512)];
  Wt[idx] = (__bf16)w;
}

// ---------------- GEMM1 (MFMA, fused cols, LDS-staged coalesced output) ----------------
// chunk y: 0 -> q (bf16), 1 -> k (bf16), 2 -> v_s (bf16), 3 -> P = v_v*v (bf16 x3)

__global__ __launch_bounds__(256) void gemm1_mfma(
    const float* __restrict__ s, const __bf16* __restrict__ Wtg,
    const float* __restrict__ bq, const float* __restrict__ bkv,
    const float* __restrict__ v,
    __bf16* __restrict__ qb, __bf16* __restrict__ nodebuf, int n)
{
  __shared__ __bf16 sA[64 * 136];
  __shared__ char uB[34816];                 // union: sB (bf16 [128][136]) / sO (f32 [64][132])
  __bf16* sB = (__bf16*)uB;
  float*  sO = (float*)uB;

  const int tid = threadIdx.x;
  const int n0 = blockIdx.x * 64;
  const int drow = tid >> 2, dseg = tid & 3;     // drain mapping
  const int dgn = n0 + drow;

  { // stage s tile -> bf16 LDS (coalesced float4 loads)
    float4 f[8];
    if (dgn < n) {
      #pragma unroll
      for (int i = 0; i < 8; i++)
        f[i] = *(const float4*)&s[(size_t)dgn * 128 + dseg * 32 + i * 4];
    } else {
      #pragma unroll
      for (int i = 0; i < 8; i++) f[i] = make_float4(0.f, 0.f, 0.f, 0.f);
    }
    #pragma unroll
    for (int i = 0; i < 4; i++) {
      bf16x8 pk;
      pk[0] = (__bf16)f[2*i].x;   pk[1] = (__bf16)f[2*i].y;
      pk[2] = (__bf16)f[2*i].z;   pk[3] = (__bf16)f[2*i].w;
      pk[4] = (__bf16)f[2*i+1].x; pk[5] = (__bf16)f[2*i+1].y;
      pk[6] = (__bf16)f[2*i+1].z; pk[7] = (__bf16)f[2*i+1].w;
      *(bf16x8*)&sA[drow * 136 + dseg * 32 + i * 8] = pk;
    }
  }

  const int wave = tid >> 6, lane = tid & 63;
  const int lr = lane & 15, lg = lane >> 4;
  bf16x8 a[4];
  bool afrag_loaded = false;

  #pragma unroll
  for (int y = 0; y < 4; y++) {
    { // stage W^T chunk y
      int row = tid >> 1, half = tid & 1;
      const __bf16* src = &Wtg[(size_t)(y * 128 + row) * 128 + half * 64];
      #pragma unroll
      for (int i = 0; i < 8; i++)
        *(bf16x8*)&sB[row * 136 + half * 64 + i * 8] = *(const bf16x8*)&src[i * 8];
    }
    __syncthreads();
    if (!afrag_loaded) {
      #pragma unroll
      for (int ks = 0; ks < 4; ks++)
        a[ks] = *(const bf16x8*)&sA[(wave * 16 + lr) * 136 + ks * 32 + lg * 8];
      afrag_loaded = true;
    }

    f32x4 acc[8];
    #pragma unroll
    for (int cf = 0; cf < 8; cf++) {
      f32x4 c = {0.f, 0.f, 0.f, 0.f};
      #pragma unroll
      for (int ks = 0; ks < 4; ks++) {
        bf16x8 b = *(const bf16x8*)&sB[(cf * 16 + lr) * 136 + ks * 32 + lg * 8];
        c = __builtin_amdgcn_mfma_f32_16x16x32_bf16(a[ks], b, c, 0, 0, 0);
      }
      acc[cf] = c;
    }
    __syncthreads();   // all waves done reading sB; safe to overwrite with sO

    #pragma unroll
    for (int cf = 0; cf < 8; cf++) {
      int cl = cf * 16 + lr;
      #pragma unroll
      for (int r = 0; r < 4; r++)
        sO[(wave * 16 + lg * 4 + r) * 132 + cl] = acc[cf][r];
    }
    __syncthreads();

    // drain: coalesced wide global I/O
    if (dgn < n) {
      if (y == 0) {
        #pragma unroll
        for (int i = 0; i < 4; i++) {
          int c0 = dseg * 32 + i * 8;
          bf16x8 pk;
          #pragma unroll
          for (int j = 0; j < 8; j++)
            pk[j] = (__bf16)(sO[drow * 132 + c0 + j] + bq[c0 + j]);
          *(bf16x8*)&qb[(size_t)dgn * 128 + c0] = pk;
        }
      } else if (y == 1 || y == 2) {
        const int boff = (y - 1) * 128;
        #pragma unroll
        for (int i = 0; i < 4; i++) {
          int c0 = dseg * 32 + i * 8;
          bf16x8 pk;
          #pragma unroll
          for (int j = 0; j < 8; j++)
            pk[j] = (__bf16)(sO[drow * 132 + c0 + j] + bkv[boff + c0 + j]);
          *(bf16x8*)&nodebuf[(size_t)dgn * 640 + boff + c0] = pk;
        }
      } else {
        float vv[32];
        #pragma unroll
        for (int j = 0; j < 32; j++)
          vv[j] = sO[drow * 132 + dseg * 32 + j] + bkv[256 + dseg * 32 + j];
        #pragma unroll
        for (int j3 = 0; j3 < 3; j3++) {
          #pragma unroll
          for (int i = 0; i < 4; i++) {
            int c0 = dseg * 32 + i * 8;
            float4 va = *(const float4*)&v[((size_t)dgn * 3 + j3) * 128 + c0];
            float4 vb = *(const float4*)&v[((size_t)dgn * 3 + j3) * 128 + c0 + 4];
            bf16x8 pk;
            pk[0] = (__bf16)(vv[i*8+0] * va.x); pk[1] = (__bf16)(vv[i*8+1] * va.y);
            pk[2] = (__bf16)(vv[i*8+2] * va.z); pk[3] = (__bf16)(vv[i*8+3] * va.w);
            pk[4] = (__bf16)(vv[i*8+4] * vb.x); pk[5] = (__bf16)(vv[i*8+5] * vb.y);
            pk[6] = (__bf16)(vv[i*8+6] * vb.z); pk[7] = (__bf16)(vv[i*8+7] * vb.w);
            *(bf16x8*)&nodebuf[(size_t)dgn * 640 + 256 + j3 * 128 + c0] = pk;
          }
        }
      }
    }
    __syncthreads();
  }
}

// ---------------- Aggregation: 4 edges x 16 lanes, DPP reduce, prefetch pipeline ----------------

__device__ inline float2 bf2f(unsigned u) {
  float2 r;
  r.x = __uint_as_float((u & 0xffffu) << 16);
  r.y = __uint_as_float(u & 0xffff0000u);
  return r;
}

__device__ __forceinline__ float dpp_add(float x, const int ctrl) {
  int t;
  switch (ctrl) {   // ctrl must be a literal per instantiation
    case 0:  t = __builtin_amdgcn_update_dpp(0, __float_as_int(x), 0xB1, 0xF, 0xF, true); break;
    case 1:  t = __builtin_amdgcn_update_dpp(0, __float_as_int(x), 0x4E, 0xF, 0xF, true); break;
    case 2:  t = __builtin_amdgcn_update_dpp(0, __float_as_int(x), 0x141, 0xF, 0xF, true); break;
    default: t = __builtin_amdgcn_update_dpp(0, __float_as_int(x), 0x140, 0xF, 0xF, true); break;
  }
  return x + __int_as_float(t);
}

// sum over each 16-lane group (VALU DPP: xor1, xor2, xor4-equiv, xor8-equiv)
__device__ __forceinline__ float row16_sum(float x) {
  x = dpp_add(x, 0);   // quad_perm [1,0,3,2]  == xor 1
  x = dpp_add(x, 1);   // quad_perm [2,3,0,1]  == xor 2
  x = dpp_add(x, 2);   // row_half_mirror      == xor 4 (post-uniform)
  x = dpp_add(x, 3);   // row_mirror           == xor 8 (post-uniform)
  return x;
}

#define ACC8(arr, vec) do { float2 _t;                                            \
  _t = bf2f(vec.x); arr[0] = fmaf(d, _t.x, arr[0]); arr[1] = fmaf(d, _t.y, arr[1]); \
  _t = bf2f(vec.y); arr[2] = fmaf(d, _t.x, arr[2]); arr[3] = fmaf(d, _t.y, arr[3]); \
  _t = bf2f(vec.z); arr[4] = fmaf(d, _t.x, arr[4]); arr[5] = fmaf(d, _t.y, arr[5]); \
  _t = bf2f(vec.w); arr[6] = fmaf(d, _t.x, arr[6]); arr[7] = fmaf(d, _t.y, arr[7]); \
} while (0)

template<bool B16>
__global__ __launch_bounds__(256) void agg_kernel(
    const int* __restrict__ off, const int* __restrict__ scol,
    const __bf16* __restrict__ qb, const char* __restrict__ nodebuf,
    const float* __restrict__ s, float* __restrict__ s_out,
    float* __restrict__ aggvf, __bf16* __restrict__ aggv16, int n)
{
  const int wid = threadIdx.x >> 6;
  const int lane = threadIdx.x & 63;
  const int nid = blockIdx.x * 4 + wid;
  if (nid >= n) return;
  const int slot = lane >> 4;
  const int fl = lane & 15;

  float qf[8];
  {
    uint4 qu = *(const uint4*)&qb[(size_t)nid * 128 + fl * 8];
    float2 t;
    t = bf2f(qu.x); qf[0] = t.x; qf[1] = t.y;
    t = bf2f(qu.y); qf[2] = t.x; qf[3] = t.y;
    t = bf2f(qu.z); qf[4] = t.x; qf[5] = t.y;
    t = bf2f(qu.w); qf[6] = t.x; qf[7] = t.y;
  }

  float acs[8], a0[8], a1[8], a2[8];
  #pragma unroll
  for (int i = 0; i < 8; i++) { acs[i] = 0.f; a0[i] = 0.f; a1[i] = 0.f; a2[i] = 0.f; }

  const int beg = off[nid];
  const int deg = off[nid + 1] - beg;

  for (int chunk = 0; chunk < deg; chunk += 64) {
    const int cc = (deg - chunk < 64) ? (deg - chunk) : 64;
    int myc = (lane < cc) ? scol[beg + chunk + lane] : 0;

    // prologue: group 0 loads
    int c0 = __shfl(myc, (slot < cc) ? slot : 0);
    const char* g = nodebuf + (size_t)c0 * 1280 + fl * 16;
    uint4 ku = *(const uint4*)(g);
    uint4 vs = *(const uint4*)(g + 256);
    uint4 p0 = *(const uint4*)(g + 512);
    uint4 p1 = *(const uint4*)(g + 768);
    uint4 p2 = *(const uint4*)(g + 1024);

    for (int j = 0; j < cc; j += 4) {
      const bool more = (j + 4 < cc);      // wave-uniform
      uint4 nku, nvs, np0, np1, np2;
      if (more) {                          // prefetch next group
        int ni = j + 4 + slot;
        int cn = __shfl(myc, (ni < cc) ? ni : 0);
        const char* gn = nodebuf + (size_t)cn * 1280 + fl * 16;
        nku = *(const uint4*)(gn);
        nvs = *(const uint4*)(gn + 256);
        np0 = *(const uint4*)(gn + 512);
        np1 = *(const uint4*)(gn + 768);
        np2 = *(const uint4*)(gn + 1024);
      }

      float2 t;
      float d = 0.f;
      t = bf2f(ku.x); d = fmaf(qf[0], t.x, d); d = fmaf(qf[1], t.y, d);
      t = bf2f(ku.y); d = fmaf(qf[2], t.x, d); d = fmaf(qf[3], t.y, d);
      t = bf2f(ku.z); d = fmaf(qf[4], t.x, d); d = fmaf(qf[5], t.y, d);
      t = bf2f(ku.w); d = fmaf(qf[6], t.x, d); d = fmaf(qf[7], t.y, d);
      d = row16_sum(d);
      if (j + slot >= cc) d = 0.f;

      ACC8(acs, vs); ACC8(a0, p0); ACC8(a1, p1); ACC8(a2, p2);

      if (more) { ku = nku; vs = nvs; p0 = np0; p1 = np1; p2 = np2; }
    }
  }

  // cross-slot reduction (once per node)
  #pragma unroll
  for (int i = 0; i < 8; i++) {
    acs[i] += __shfl_xor(acs[i], 16); acs[i] += __shfl_xor(acs[i], 32);
    a0[i]  += __shfl_xor(a0[i], 16);  a0[i]  += __shfl_xor(a0[i], 32);
    a1[i]  += __shfl_xor(a1[i], 16);  a1[i]  += __shfl_xor(a1[i], 32);
    a2[i]  += __shfl_xor(a2[i], 16);  a2[i]  += __shfl_xor(a2[i], 32);
  }

  if (slot == 0) {
    const float* sp = &s[(size_t)nid * 128 + fl * 8];
    float4 w0, w1;
    w0.x = acs[0] + sp[0]; w0.y = acs[1] + sp[1]; w0.z = acs[2] + sp[2]; w0.w = acs[3] + sp[3];
    w1.x = acs[4] + sp[4]; w1.y = acs[5] + sp[5]; w1.z = acs[6] + sp[6]; w1.w = acs[7] + sp[7];
    *(float4*)&s_out[(size_t)nid * 128 + fl * 8] = w0;
    *(float4*)&s_out[(size_t)nid * 128 + fl * 8 + 4] = w1;

    if (B16) {
      bf16x8 pk;
      #pragma unroll
      for (int j = 0; j < 8; j++) pk[j] = (__bf16)a0[j];
      *(bf16x8*)&aggv16[((size_t)nid * 3 + 0) * 128 + fl * 8] = pk;
      #pragma unroll
      for (int j = 0; j < 8; j++) pk[j] = (__bf16)a1[j];
      *(bf16x8*)&aggv16[((size_t)nid * 3 + 1) * 128 + fl * 8] = pk;
      #pragma unroll
      for (int j = 0; j < 8; j++) pk[j] = (__bf16)a2[j];
      *(bf16x8*)&aggv16[((size_t)nid * 3 + 2) * 128 + fl * 8] = pk;
    } else {
      float* av = &aggvf[(size_t)nid * 384 + fl * 8];
      float4 u0, u1;
      u0.x = a0[0]; u0.y = a0[1]; u0.z = a0[2]; u0.w = a0[3];
      u1.x = a0[4]; u1.y = a0[5]; u1.z = a0[6]; u1.w = a0[7];
      *(float4*)&av[0] = u0; *(float4*)&av[4] = u1;
      u0.x = a1[0]; u0.y = a1[1]; u0.z = a1[2]; u0.w = a1[3];
      u1.x = a1[4]; u1.y = a1[5]; u1.z = a1[6]; u1.w = a1[7];
      *(float4*)&av[128] = u0; *(float4*)&av[132] = u1;
      u0.x = a2[0]; u0.y = a2[1]; u0.z = a2[2]; u0.w = a2[3];
      u1.x = a2[4]; u1.y = a2[5]; u1.z = a2[6]; u1.w = a2[7];
      *(float4*)&av[256] = u0; *(float4*)&av[260] = u1;
    }
  }
}

// ---------------- GEMM2 (MFMA, LDS-staged coalesced output): vout = v + aggv @ Wvec + bvec ----------------

template<bool B16>
__global__ __launch_bounds__(256) void gemm2_mfma(
    const __bf16* __restrict__ Wtg,   // rows 512..639 = Wvec^T
    const float* __restrict__ bvec, const float* __restrict__ v,
    const __bf16* __restrict__ aggv16, float* __restrict__ vout, int rows)
{
  __shared__ __bf16 sA[64 * 136];
  __shared__ char uB[34816];
  __bf16* sB = (__bf16*)uB;
  float*  sO = (float*)uB;

  const int tid = threadIdx.x;
  const int r0 = blockIdx.x * 64;
  const int drow = tid >> 2, dseg = tid & 3;
  const int dgr = r0 + drow;

  if (B16) {  // stage A tile directly from bf16 aggv
    #pragma unroll
    for (int i = 0; i < 4; i++) {
      bf16x8 pk = {0,0,0,0,0,0,0,0};
      if (dgr < rows) pk = *(const bf16x8*)&aggv16[(size_t)dgr * 128 + dseg * 32 + i * 8];
      *(bf16x8*)&sA[drow * 136 + dseg * 32 + i * 8] = pk;
    }
  } else {    // stage A tile (f32 -> bf16, coalesced), in-place source
    float4 f[8];
    if (dgr < rows) {
      #pragma unroll
      for (int i = 0; i < 8; i++)
        f[i] = *(const float4*)&vout[(size_t)dgr * 128 + dseg * 32 + i * 4];
    } else {
      #pragma unroll
      for (int i = 0; i < 8; i++) f[i] = make_float4(0.f, 0.f, 0.f, 0.f);
    }
    #pragma unroll
    for (int i = 0; i < 4; i++) {
      bf16x8 pk;
      pk[0] = (__bf16)f[2*i].x;   pk[1] = (__bf16)f[2*i].y;
      pk[2] = (__bf16)f[2*i].z;   pk[3] = (__bf16)f[2*i].w;
      pk[4] = (__bf16)f[2*i+1].x; pk[5] = (__bf16)f[2*i+1].y;
      pk[6] = (__bf16)f[2*i+1].z; pk[7] = (__bf16)f[2*i+1].w;
      *(bf16x8*)&sA[drow * 136 + dseg * 32 + i * 8] = pk;
    }
  }
  { // stage Wvec^T
    int row = tid >> 1, half = tid & 1;
    const __bf16* src = &Wtg[(size_t)(512 + row) * 128 + half * 64];
    #pragma unroll
    for (int i = 0; i < 8; i++)
      *(bf16x8*)&sB[row * 136 + half * 64 + i * 8] = *(const bf16x8*)&src[i * 8];
  }
  __syncthreads();

  const int wave = tid >> 6, lane = tid & 63;
  const int lr = lane & 15, lg = lane >> 4;

  bf16x8 a[4];
  #pragma unroll
  for (int ks = 0; ks < 4; ks++)
    a[ks] = *(const bf16x8*)&sA[(wave * 16 + lr) * 136 + ks * 32 + lg * 8];

  f32x4 acc[8];
  #pragma unroll
  for (int cf = 0; cf < 8; cf++) {
    f32x4 c = {0.f, 0.f, 0.f, 0.f};
    #pragma unroll
    for (int ks = 0; ks < 4; ks++) {
      bf16x8 b = *(const bf16x8*)&sB[(cf * 16 + lr) * 136 + ks * 32 + lg * 8];
      c = __builtin_amdgcn_mfma_f32_16x16x32_bf16(a[ks], b, c, 0, 0, 0);
    }
    acc[cf] = c;
  }
  __syncthreads();   // done reading sB

  #pragma unroll
  for (int cf = 0; cf < 8; cf++) {
    int cl = cf * 16 + lr;
    #pragma unroll
    for (int r = 0; r < 4; r++)
      sO[(wave * 16 + lg * 4 + r) * 132 + cl] = acc[cf][r];
  }
  __syncthreads();

  if (dgr < rows) {
    #pragma unroll
    for (int i = 0; i < 8; i++) {
      int c0 = dseg * 32 + i * 4;
      float4 va = *(const float4*)&v[(size_t)dgr * 128 + c0];
      float4 o;
      o.x = sO[drow * 132 + c0 + 0] + va.x + bvec[c0 + 0];
      o.y = sO[drow * 132 + c0 + 1] + va.y + bvec[c0 + 1];
      o.z = sO[drow * 132 + c0 + 2] + va.z + bvec[c0 + 2];
      o.w = sO[drow * 132 + c0 + 3] + va.w + bvec[c0 + 3];
      *(float4*)&vout[(size_t)dgr * 128 + c0] = o;
    }
  }
}

// ---------------- launch ----------------

extern "C" void kernel_launch(void* const* d_in, const int* in_sizes, int n_in,
                              void* d_out, int out_size, void* d_ws, size_t ws_size,
                              hipStream_t stream)
{
  const float* s    = (const float*)d_in[0];
  const float* v    = (const float*)d_in[1];
  const int*   ei   = (const int*)d_in[2];
  const float* Wq   = (const float*)d_in[3];
  const float* bq   = (const float*)d_in[4];
  const float* Wkv  = (const float*)d_in[5];
  const float* bkv  = (const float*)d_in[6];
  const float* Wvec = (const float*)d_in[7];
  const float* bvec = (const float*)d_in[8];

  const int N = in_sizes[0] / 128;
  const int E = in_sizes[2] / 2;
  const int* row = ei;
  const int* col = ei + E;

  char* ws = (char*)d_ws;
  size_t o = 0;
  auto alloc = [&](size_t bytes) -> char* {
    char* p = ws + o;
    o = (o + bytes + 255) & ~(size_t)255;
    return p;
  };
  int* off    = (int*)alloc((size_t)(N + 1) * 4);
  int* cursor = (int*)alloc((size_t)N * 4);
  int* scol   = (int*)alloc((size_t)E * 4);
  __bf16* qb      = (__bf16*)alloc((size_t)N * 128 * 2);
  __bf16* nodebuf = (__bf16*)alloc((size_t)N * 640 * 2);
  __bf16* Wt      = (__bf16*)alloc((size_t)640 * 128 * 2);
  __bf16* aggv16  = (__bf16*)alloc((size_t)N * 384 * 2);
  const bool b16 = (o <= ws_size);

  float* s_out = (float*)d_out;
  float* aggv  = (float*)d_out + (size_t)N * 128;   // f32 staging / final v_out

  // CSR build
  hipMemsetAsync(cursor, 0, (size_t)N * 4, stream);
  hist_kernel<<<(E + 255) / 256, 256, 0, stream>>>(row, cursor, E);
  scan_kernel<<<1, 1024, 0, stream>>>(cursor, off, cursor, N, E);
  scatter_kernel<<<(E + 255) / 256, 256, 0, stream>>>(row, col, cursor, scol, E);

  // weight prep + node features
  wprep_kernel<<<320, 256, 0, stream>>>(Wq, Wkv, Wvec, Wt);
  gemm1_mfma<<<(N + 63) / 64, 256, 0, stream>>>(s, Wt, bq, bkv, v, qb, nodebuf, N);

  // edge aggregation
  if (b16)
    agg_kernel<true><<<(N + 3) / 4, 256, 0, stream>>>(off, scol, qb, (const char*)nodebuf,
                                                      s, s_out, aggv, aggv16, N);
  else
    agg_kernel<false><<<(N + 3) / 4, 256, 0, stream>>>(off, scol, qb, (const char*)nodebuf,
                                                       s, s_out, aggv, aggv16, N);

  // v_out GEMM
  if (b16)
    gemm2_mfma<true><<<(3 * N + 63) / 64, 256, 0, stream>>>(Wt, bvec, v, aggv16, aggv, 3 * N);
  else
    gemm2_mfma<false><<<(3 * N + 63) / 64, 256, 0, stream>>>(Wt, bvec, v, aggv16, aggv, 3 * N);
}

// Round 8
// 321.187 us; speedup vs baseline: 1.4800x; 1.2968x over previous
//
#include <hip/hip_runtime.h>
#include <hip/hip_bf16.h>

typedef __attribute__((ext_vector_type(8))) __bf16 bf16x8;
typedef __attribute__((ext_vector_type(4))) float f32x4;

// ---------------- CSR build ----------------

__global__ void hist_kernel(const int* __restrict__ row, int* __restrict__ cnt, int e) {
  int i = blockIdx.x * 256 + threadIdx.x;
  if (i < e) atomicAdd(&cnt[row[i]], 1);
}

__global__ __launch_bounds__(1024) void scan1_kernel(const int* __restrict__ cnt, int* __restrict__ off,
                                                     int* __restrict__ bsum, int n) {
  __shared__ int sh[1024];
  int tid = threadIdx.x;
  int i = blockIdx.x * 1024 + tid;
  int v = (i < n) ? cnt[i] : 0;
  sh[tid] = v;
  __syncthreads();
  for (int d = 1; d < 1024; d <<= 1) {
    int t = (tid >= d) ? sh[tid - d] : 0;
    __syncthreads();
    sh[tid] += t;
    __syncthreads();
  }
  if (i < n) off[i] = sh[tid] - v;       // exclusive within block
  if (tid == 1023) bsum[blockIdx.x] = sh[1023];
}

__global__ void scan2_kernel(int* bsum, int nb) {
  if (blockIdx.x == 0 && threadIdx.x == 0) {
    int run = 0;
    for (int b = 0; b < nb; b++) { int t = bsum[b]; bsum[b] = run; run += t; }
  }
}

__global__ __launch_bounds__(1024) void scan3_kernel(const int* __restrict__ bsum, int* __restrict__ off,
                                                     int* __restrict__ cursor, int n, int e) {
  int i = blockIdx.x * 1024 + threadIdx.x;
  if (i < n) { int o = off[i] + bsum[blockIdx.x]; off[i] = o; cursor[i] = o; }
  if (i == 0) off[n] = e;
}

__global__ void scatter_kernel(const int* __restrict__ row, const int* __restrict__ col,
                               int* __restrict__ cursor, int* __restrict__ scol, int e) {
  int i = blockIdx.x * 256 + threadIdx.x;
  if (i < e) { int r = row[i]; int pos = atomicAdd(&cursor[r], 1); scol[pos] = col[i]; }
}

// ---------------- W prep: Wt[c][k] = bf16(W[k][c]), c in [0,640) = q|kv|vec ----------------

__global__ void wprep_kernel(const float* __restrict__ Wq, const float* __restrict__ Wkv,
                             const float* __restrict__ Wvec, __bf16* __restrict__ Wt) {
  int idx = blockIdx.x * 256 + threadIdx.x;      // 640*128 = 81920
  int c = idx >> 7, k = idx & 127;
  float w;
  if (c < 128)      w = Wq[k * 128 + c];
  else if (c < 512) w = Wkv[k * 384 + (c - 128)];
  else              w = Wvec[k * 128 + (c - 512)];
  Wt[idx] = (__bf16)w;
}

// ---------------- GEMM1 (MFMA): 64 rows x one 128-col chunk per block ----------------
// blockIdx.y: 0 -> q (bf16), 1 -> k (bf16), 2 -> v_s (bf16), 3 -> P = v_v*v (bf16 x3)

__global__ __launch_bounds__(256) void gemm1_mfma(
    const float* __restrict__ s, const __bf16* __restrict__ Wtg,
    const float* __restrict__ bq, const float* __restrict__ bkv,
    const float* __restrict__ v,
    __bf16* __restrict__ qb, __bf16* __restrict__ nodebuf, int n)
{
  __shared__ __bf16 sA[64 * 136];
  __shared__ char uB[34816];                 // union: sB (bf16 [128][136]) / sO (f32 [64][132])
  __bf16* sB = (__bf16*)uB;
  float*  sO = (float*)uB;

  const int tid = threadIdx.x;
  const int y = blockIdx.y;
  const int n0 = blockIdx.x * 64;
  const int drow = tid >> 2, dseg = tid & 3;     // stage/drain mapping
  const int dgn = n0 + drow;

  { // stage s tile -> bf16 LDS (coalesced float4 loads)
    float4 f[8];
    if (dgn < n) {
      #pragma unroll
      for (int i = 0; i < 8; i++)
        f[i] = *(const float4*)&s[(size_t)dgn * 128 + dseg * 32 + i * 4];
    } else {
      #pragma unroll
      for (int i = 0; i < 8; i++) f[i] = make_float4(0.f, 0.f, 0.f, 0.f);
    }
    #pragma unroll
    for (int i = 0; i < 4; i++) {
      bf16x8 pk;
      pk[0] = (__bf16)f[2*i].x;   pk[1] = (__bf16)f[2*i].y;
      pk[2] = (__bf16)f[2*i].z;   pk[3] = (__bf16)f[2*i].w;
      pk[4] = (__bf16)f[2*i+1].x; pk[5] = (__bf16)f[2*i+1].y;
      pk[6] = (__bf16)f[2*i+1].z; pk[7] = (__bf16)f[2*i+1].w;
      *(bf16x8*)&sA[drow * 136 + dseg * 32 + i * 8] = pk;
    }
  }
  { // stage W^T chunk y
    int row = tid >> 1, half = tid & 1;
    const __bf16* src = &Wtg[(size_t)(y * 128 + row) * 128 + half * 64];
    #pragma unroll
    for (int i = 0; i < 8; i++)
      *(bf16x8*)&sB[row * 136 + half * 64 + i * 8] = *(const bf16x8*)&src[i * 8];
  }
  __syncthreads();

  const int wave = tid >> 6, lane = tid & 63;
  const int lr = lane & 15, lg = lane >> 4;

  bf16x8 a[4];
  #pragma unroll
  for (int ks = 0; ks < 4; ks++)
    a[ks] = *(const bf16x8*)&sA[(wave * 16 + lr) * 136 + ks * 32 + lg * 8];

  f32x4 acc[8];
  #pragma unroll
  for (int cf = 0; cf < 8; cf++) {
    f32x4 c = {0.f, 0.f, 0.f, 0.f};
    #pragma unroll
    for (int ks = 0; ks < 4; ks++) {
      bf16x8 b = *(const bf16x8*)&sB[(cf * 16 + lr) * 136 + ks * 32 + lg * 8];
      c = __builtin_amdgcn_mfma_f32_16x16x32_bf16(a[ks], b, c, 0, 0, 0);
    }
    acc[cf] = c;
  }
  __syncthreads();   // all waves done reading sB

  #pragma unroll
  for (int cf = 0; cf < 8; cf++) {
    int cl = cf * 16 + lr;
    #pragma unroll
    for (int r = 0; r < 4; r++)
      sO[(wave * 16 + lg * 4 + r) * 132 + cl] = acc[cf][r];
  }
  __syncthreads();

  // drain: coalesced wide global I/O
  if (dgn < n) {
    if (y == 0) {
      #pragma unroll
      for (int i = 0; i < 4; i++) {
        int c0 = dseg * 32 + i * 8;
        bf16x8 pk;
        #pragma unroll
        for (int j = 0; j < 8; j++)
          pk[j] = (__bf16)(sO[drow * 132 + c0 + j] + bq[c0 + j]);
        *(bf16x8*)&qb[(size_t)dgn * 128 + c0] = pk;
      }
    } else if (y == 1 || y == 2) {
      const int boff = (y - 1) * 128;
      #pragma unroll
      for (int i = 0; i < 4; i++) {
        int c0 = dseg * 32 + i * 8;
        bf16x8 pk;
        #pragma unroll
        for (int j = 0; j < 8; j++)
          pk[j] = (__bf16)(sO[drow * 132 + c0 + j] + bkv[boff + c0 + j]);
        *(bf16x8*)&nodebuf[(size_t)dgn * 640 + boff + c0] = pk;
      }
    } else {
      float vv[32];
      #pragma unroll
      for (int j = 0; j < 32; j++)
        vv[j] = sO[drow * 132 + dseg * 32 + j] + bkv[256 + dseg * 32 + j];
      #pragma unroll
      for (int j3 = 0; j3 < 3; j3++) {
        #pragma unroll
        for (int i = 0; i < 4; i++) {
          int c0 = dseg * 32 + i * 8;
          float4 va = *(const float4*)&v[((size_t)dgn * 3 + j3) * 128 + c0];
          float4 vb = *(const float4*)&v[((size_t)dgn * 3 + j3) * 128 + c0 + 4];
          bf16x8 pk;
          pk[0] = (__bf16)(vv[i*8+0] * va.x); pk[1] = (__bf16)(vv[i*8+1] * va.y);
          pk[2] = (__bf16)(vv[i*8+2] * va.z); pk[3] = (__bf16)(vv[i*8+3] * va.w);
          pk[4] = (__bf16)(vv[i*8+4] * vb.x); pk[5] = (__bf16)(vv[i*8+5] * vb.y);
          pk[6] = (__bf16)(vv[i*8+6] * vb.z); pk[7] = (__bf16)(vv[i*8+7] * vb.w);
          *(bf16x8*)&nodebuf[(size_t)dgn * 640 + 256 + j3 * 128 + c0] = pk;
        }
      }
    }
  }
}

// ---------------- Aggregation: 4 edges x 16 lanes, DPP reduce, prefetch, packed accum ----------------

__device__ inline float2 bf2f(unsigned u) {
  float2 r;
  r.x = __uint_as_float((u & 0xffffu) << 16);
  r.y = __uint_as_float(u & 0xffff0000u);
  return r;
}

__device__ __forceinline__ float dpp_add(float x, const int ctrl) {
  int t;
  switch (ctrl) {
    case 0:  t = __builtin_amdgcn_update_dpp(0, __float_as_int(x), 0xB1, 0xF, 0xF, true); break;
    case 1:  t = __builtin_amdgcn_update_dpp(0, __float_as_int(x), 0x4E, 0xF, 0xF, true); break;
    case 2:  t = __builtin_amdgcn_update_dpp(0, __float_as_int(x), 0x141, 0xF, 0xF, true); break;
    default: t = __builtin_amdgcn_update_dpp(0, __float_as_int(x), 0x140, 0xF, 0xF, true); break;
  }
  return x + __int_as_float(t);
}

__device__ __forceinline__ float row16_sum(float x) {
  x = dpp_add(x, 0);
  x = dpp_add(x, 1);
  x = dpp_add(x, 2);
  x = dpp_add(x, 3);
  return x;
}

#define ACCP(arr, vec) do { float2 _t;                                                \
  _t = bf2f(vec.x); arr[0].x = fmaf(d, _t.x, arr[0].x); arr[0].y = fmaf(d, _t.y, arr[0].y); \
  _t = bf2f(vec.y); arr[1].x = fmaf(d, _t.x, arr[1].x); arr[1].y = fmaf(d, _t.y, arr[1].y); \
  _t = bf2f(vec.z); arr[2].x = fmaf(d, _t.x, arr[2].x); arr[2].y = fmaf(d, _t.y, arr[2].y); \
  _t = bf2f(vec.w); arr[3].x = fmaf(d, _t.x, arr[3].x); arr[3].y = fmaf(d, _t.y, arr[3].y); \
} while (0)

template<bool B16>
__global__ __launch_bounds__(256) void agg_kernel(
    const int* __restrict__ off, const int* __restrict__ scol,
    const __bf16* __restrict__ qb, const char* __restrict__ nodebuf,
    const float* __restrict__ s, float* __restrict__ s_out,
    float* __restrict__ aggvf, __bf16* __restrict__ aggv16, int n)
{
  const int wid = threadIdx.x >> 6;
  const int lane = threadIdx.x & 63;
  const int nid = blockIdx.x * 4 + wid;
  if (nid >= n) return;
  const int slot = lane >> 4;
  const int fl = lane & 15;

  float qf[8];
  {
    uint4 qu = *(const uint4*)&qb[(size_t)nid * 128 + fl * 8];
    float2 t;
    t = bf2f(qu.x); qf[0] = t.x; qf[1] = t.y;
    t = bf2f(qu.y); qf[2] = t.x; qf[3] = t.y;
    t = bf2f(qu.z); qf[4] = t.x; qf[5] = t.y;
    t = bf2f(qu.w); qf[6] = t.x; qf[7] = t.y;
  }

  float2 acs[4], a0[4], a1[4], a2[4];
  #pragma unroll
  for (int i = 0; i < 4; i++) {
    acs[i] = make_float2(0.f, 0.f); a0[i] = make_float2(0.f, 0.f);
    a1[i] = make_float2(0.f, 0.f); a2[i] = make_float2(0.f, 0.f);
  }

  const int beg = off[nid];
  const int deg = off[nid + 1] - beg;

  for (int chunk = 0; chunk < deg; chunk += 64) {
    const int cc = (deg - chunk < 64) ? (deg - chunk) : 64;
    int myc = (lane < cc) ? scol[beg + chunk + lane] : 0;

    int c0 = __shfl(myc, (slot < cc) ? slot : 0);
    const char* g = nodebuf + (size_t)c0 * 1280 + fl * 16;
    uint4 ku = *(const uint4*)(g);
    uint4 vs = *(const uint4*)(g + 256);
    uint4 p0 = *(const uint4*)(g + 512);
    uint4 p1 = *(const uint4*)(g + 768);
    uint4 p2 = *(const uint4*)(g + 1024);

    for (int j = 0; j < cc; j += 4) {
      const bool more = (j + 4 < cc);
      uint4 nku, nvs, np0, np1, np2;
      if (more) {
        int ni = j + 4 + slot;
        int cn = __shfl(myc, (ni < cc) ? ni : 0);
        const char* gn = nodebuf + (size_t)cn * 1280 + fl * 16;
        nku = *(const uint4*)(gn);
        nvs = *(const uint4*)(gn + 256);
        np0 = *(const uint4*)(gn + 512);
        np1 = *(const uint4*)(gn + 768);
        np2 = *(const uint4*)(gn + 1024);
      }

      float2 t;
      float d = 0.f;
      t = bf2f(ku.x); d = fmaf(qf[0], t.x, d); d = fmaf(qf[1], t.y, d);
      t = bf2f(ku.y); d = fmaf(qf[2], t.x, d); d = fmaf(qf[3], t.y, d);
      t = bf2f(ku.z); d = fmaf(qf[4], t.x, d); d = fmaf(qf[5], t.y, d);
      t = bf2f(ku.w); d = fmaf(qf[6], t.x, d); d = fmaf(qf[7], t.y, d);
      d = row16_sum(d);
      if (j + slot >= cc) d = 0.f;

      ACCP(acs, vs); ACCP(a0, p0); ACCP(a1, p1); ACCP(a2, p2);

      if (more) { ku = nku; vs = nvs; p0 = np0; p1 = np1; p2 = np2; }
    }
  }

  // cross-slot reduction
  #pragma unroll
  for (int i = 0; i < 4; i++) {
    acs[i].x += __shfl_xor(acs[i].x, 16); acs[i].x += __shfl_xor(acs[i].x, 32);
    acs[i].y += __shfl_xor(acs[i].y, 16); acs[i].y += __shfl_xor(acs[i].y, 32);
    a0[i].x  += __shfl_xor(a0[i].x, 16);  a0[i].x  += __shfl_xor(a0[i].x, 32);
    a0[i].y  += __shfl_xor(a0[i].y, 16);  a0[i].y  += __shfl_xor(a0[i].y, 32);
    a1[i].x  += __shfl_xor(a1[i].x, 16);  a1[i].x  += __shfl_xor(a1[i].x, 32);
    a1[i].y  += __shfl_xor(a1[i].y, 16);  a1[i].y  += __shfl_xor(a1[i].y, 32);
    a2[i].x  += __shfl_xor(a2[i].x, 16);  a2[i].x  += __shfl_xor(a2[i].x, 32);
    a2[i].y  += __shfl_xor(a2[i].y, 16);  a2[i].y  += __shfl_xor(a2[i].y, 32);
  }

  if (slot == 0) {
    const float* sp = &s[(size_t)nid * 128 + fl * 8];
    float4 w0, w1;
    w0.x = acs[0].x + sp[0]; w0.y = acs[0].y + sp[1];
    w0.z = acs[1].x + sp[2]; w0.w = acs[1].y + sp[3];
    w1.x = acs[2].x + sp[4]; w1.y = acs[2].y + sp[5];
    w1.z = acs[3].x + sp[6]; w1.w = acs[3].y + sp[7];
    *(float4*)&s_out[(size_t)nid * 128 + fl * 8] = w0;
    *(float4*)&s_out[(size_t)nid * 128 + fl * 8 + 4] = w1;

    if (B16) {
      bf16x8 pk;
      pk[0] = (__bf16)a0[0].x; pk[1] = (__bf16)a0[0].y; pk[2] = (__bf16)a0[1].x; pk[3] = (__bf16)a0[1].y;
      pk[4] = (__bf16)a0[2].x; pk[5] = (__bf16)a0[2].y; pk[6] = (__bf16)a0[3].x; pk[7] = (__bf16)a0[3].y;
      *(bf16x8*)&aggv16[((size_t)nid * 3 + 0) * 128 + fl * 8] = pk;
      pk[0] = (__bf16)a1[0].x; pk[1] = (__bf16)a1[0].y; pk[2] = (__bf16)a1[1].x; pk[3] = (__bf16)a1[1].y;
      pk[4] = (__bf16)a1[2].x; pk[5] = (__bf16)a1[2].y; pk[6] = (__bf16)a1[3].x; pk[7] = (__bf16)a1[3].y;
      *(bf16x8*)&aggv16[((size_t)nid * 3 + 1) * 128 + fl * 8] = pk;
      pk[0] = (__bf16)a2[0].x; pk[1] = (__bf16)a2[0].y; pk[2] = (__bf16)a2[1].x; pk[3] = (__bf16)a2[1].y;
      pk[4] = (__bf16)a2[2].x; pk[5] = (__bf16)a2[2].y; pk[6] = (__bf16)a2[3].x; pk[7] = (__bf16)a2[3].y;
      *(bf16x8*)&aggv16[((size_t)nid * 3 + 2) * 128 + fl * 8] = pk;
    } else {
      float* av = &aggvf[(size_t)nid * 384 + fl * 8];
      *(float4*)&av[0]   = make_float4(a0[0].x, a0[0].y, a0[1].x, a0[1].y);
      *(float4*)&av[4]   = make_float4(a0[2].x, a0[2].y, a0[3].x, a0[3].y);
      *(float4*)&av[128] = make_float4(a1[0].x, a1[0].y, a1[1].x, a1[1].y);
      *(float4*)&av[132] = make_float4(a1[2].x, a1[2].y, a1[3].x, a1[3].y);
      *(float4*)&av[256] = make_float4(a2[0].x, a2[0].y, a2[1].x, a2[1].y);
      *(float4*)&av[260] = make_float4(a2[2].x, a2[2].y, a2[3].x, a2[3].y);
    }
  }
}

// ---------------- GEMM2 (MFMA, LDS-staged coalesced output): vout = v + aggv @ Wvec + bvec ----------------

template<bool B16>
__global__ __launch_bounds__(256) void gemm2_mfma(
    const __bf16* __restrict__ Wtg,   // rows 512..639 = Wvec^T
    const float* __restrict__ bvec, const float* __restrict__ v,
    const __bf16* __restrict__ aggv16, float* __restrict__ vout, int rows)
{
  __shared__ __bf16 sA[64 * 136];
  __shared__ char uB[34816];
  __bf16* sB = (__bf16*)uB;
  float*  sO = (float*)uB;

  const int tid = threadIdx.x;
  const int r0 = blockIdx.x * 64;
  const int drow = tid >> 2, dseg = tid & 3;
  const int dgr = r0 + drow;

  if (B16) {
    #pragma unroll
    for (int i = 0; i < 4; i++) {
      bf16x8 pk = {0,0,0,0,0,0,0,0};
      if (dgr < rows) pk = *(const bf16x8*)&aggv16[(size_t)dgr * 128 + dseg * 32 + i * 8];
      *(bf16x8*)&sA[drow * 136 + dseg * 32 + i * 8] = pk;
    }
  } else {
    float4 f[8];
    if (dgr < rows) {
      #pragma unroll
      for (int i = 0; i < 8; i++)
        f[i] = *(const float4*)&vout[(size_t)dgr * 128 + dseg * 32 + i * 4];
    } else {
      #pragma unroll
      for (int i = 0; i < 8; i++) f[i] = make_float4(0.f, 0.f, 0.f, 0.f);
    }
    #pragma unroll
    for (int i = 0; i < 4; i++) {
      bf16x8 pk;
      pk[0] = (__bf16)f[2*i].x;   pk[1] = (__bf16)f[2*i].y;
      pk[2] = (__bf16)f[2*i].z;   pk[3] = (__bf16)f[2*i].w;
      pk[4] = (__bf16)f[2*i+1].x; pk[5] = (__bf16)f[2*i+1].y;
      pk[6] = (__bf16)f[2*i+1].z; pk[7] = (__bf16)f[2*i+1].w;
      *(bf16x8*)&sA[drow * 136 + dseg * 32 + i * 8] = pk;
    }
  }
  { // stage Wvec^T
    int row = tid >> 1, half = tid & 1;
    const __bf16* src = &Wtg[(size_t)(512 + row) * 128 + half * 64];
    #pragma unroll
    for (int i = 0; i < 8; i++)
      *(bf16x8*)&sB[row * 136 + half * 64 + i * 8] = *(const bf16x8*)&src[i * 8];
  }
  __syncthreads();

  const int wave = tid >> 6, lane = tid & 63;
  const int lr = lane & 15, lg = lane >> 4;

  bf16x8 a[4];
  #pragma unroll
  for (int ks = 0; ks < 4; ks++)
    a[ks] = *(const bf16x8*)&sA[(wave * 16 + lr) * 136 + ks * 32 + lg * 8];

  f32x4 acc[8];
  #pragma unroll
  for (int cf = 0; cf < 8; cf++) {
    f32x4 c = {0.f, 0.f, 0.f, 0.f};
    #pragma unroll
    for (int ks = 0; ks < 4; ks++) {
      bf16x8 b = *(const bf16x8*)&sB[(cf * 16 + lr) * 136 + ks * 32 + lg * 8];
      c = __builtin_amdgcn_mfma_f32_16x16x32_bf16(a[ks], b, c, 0, 0, 0);
    }
    acc[cf] = c;
  }
  __syncthreads();

  #pragma unroll
  for (int cf = 0; cf < 8; cf++) {
    int cl = cf * 16 + lr;
    #pragma unroll
    for (int r = 0; r < 4; r++)
      sO[(wave * 16 + lg * 4 + r) * 132 + cl] = acc[cf][r];
  }
  __syncthreads();

  if (dgr < rows) {
    #pragma unroll
    for (int i = 0; i < 8; i++) {
      int c0 = dseg * 32 + i * 4;
      float4 va = *(const float4*)&v[(size_t)dgr * 128 + c0];
      float4 o;
      o.x = sO[drow * 132 + c0 + 0] + va.x + bvec[c0 + 0];
      o.y = sO[drow * 132 + c0 + 1] + va.y + bvec[c0 + 1];
      o.z = sO[drow * 132 + c0 + 2] + va.z + bvec[c0 + 2];
      o.w = sO[drow * 132 + c0 + 3] + va.w + bvec[c0 + 3];
      *(float4*)&vout[(size_t)dgr * 128 + c0] = o;
    }
  }
}

// ---------------- launch ----------------

extern "C" void kernel_launch(void* const* d_in, const int* in_sizes, int n_in,
                              void* d_out, int out_size, void* d_ws, size_t ws_size,
                              hipStream_t stream)
{
  const float* s    = (const float*)d_in[0];
  const float* v    = (const float*)d_in[1];
  const int*   ei   = (const int*)d_in[2];
  const float* Wq   = (const float*)d_in[3];
  const float* bq   = (const float*)d_in[4];
  const float* Wkv  = (const float*)d_in[5];
  const float* bkv  = (const float*)d_in[6];
  const float* Wvec = (const float*)d_in[7];
  const float* bvec = (const float*)d_in[8];

  const int N = in_sizes[0] / 128;
  const int E = in_sizes[2] / 2;
  const int* row = ei;
  const int* col = ei + E;

  char* ws = (char*)d_ws;
  size_t o = 0;
  auto alloc = [&](size_t bytes) -> char* {
    char* p = ws + o;
    o = (o + bytes + 255) & ~(size_t)255;
    return p;
  };
  int* off    = (int*)alloc((size_t)(N + 1) * 4);
  int* cursor = (int*)alloc((size_t)N * 4);
  int* bsum   = (int*)alloc(4096);
  int* scol   = (int*)alloc((size_t)E * 4);
  __bf16* qb      = (__bf16*)alloc((size_t)N * 128 * 2);
  __bf16* nodebuf = (__bf16*)alloc((size_t)N * 640 * 2);
  __bf16* Wt      = (__bf16*)alloc((size_t)640 * 128 * 2);
  __bf16* aggv16  = (__bf16*)alloc((size_t)N * 384 * 2);
  const bool b16 = (o <= ws_size);

  float* s_out = (float*)d_out;
  float* aggv  = (float*)d_out + (size_t)N * 128;

  // CSR build
  hipMemsetAsync(cursor, 0, (size_t)N * 4, stream);
  hist_kernel<<<(E + 255) / 256, 256, 0, stream>>>(row, cursor, E);
  int nb = (N + 1023) / 1024;
  scan1_kernel<<<nb, 1024, 0, stream>>>(cursor, off, bsum, N);
  scan2_kernel<<<1, 64, 0, stream>>>(bsum, nb);
  scan3_kernel<<<nb, 1024, 0, stream>>>(bsum, off, cursor, N, E);
  scatter_kernel<<<(E + 255) / 256, 256, 0, stream>>>(row, col, cursor, scol, E);

  // weight prep + node features (per-chunk blocks)
  wprep_kernel<<<320, 256, 0, stream>>>(Wq, Wkv, Wvec, Wt);
  dim3 g1((N + 63) / 64, 4);
  gemm1_mfma<<<g1, 256, 0, stream>>>(s, Wt, bq, bkv, v, qb, nodebuf, N);

  // edge aggregation
  if (b16)
    agg_kernel<true><<<(N + 3) / 4, 256, 0, stream>>>(off, scol, qb, (const char*)nodebuf,
                                                      s, s_out, aggv, aggv16, N);
  else
    agg_kernel<false><<<(N + 3) / 4, 256, 0, stream>>>(off, scol, qb, (const char*)nodebuf,
                                                       s, s_out, aggv, aggv16, N);

  // v_out GEMM
  if (b16)
    gemm2_mfma<true><<<(3 * N + 63) / 64, 256, 0, stream>>>(Wt, bvec, v, aggv16, aggv, 3 * N);
  else
    gemm2_mfma<false><<<(3 * N + 63) / 64, 256, 0, stream>>>(Wt, bvec, v, aggv16, aggv, 3 * N);
}

// Round 9
// 310.952 us; speedup vs baseline: 1.5287x; 1.0329x over previous
//
#include <hip/hip_runtime.h>
#include <hip/hip_bf16.h>

typedef __attribute__((ext_vector_type(8))) __bf16 bf16x8;
typedef __attribute__((ext_vector_type(4))) float f32x4;

// ---------------- CSR build + W prep (merged) ----------------

__global__ void hist_wprep_kernel(const int* __restrict__ row, int* __restrict__ cnt, int e,
                                  const float* __restrict__ Wq, const float* __restrict__ Wkv,
                                  const float* __restrict__ Wvec, __bf16* __restrict__ Wt,
                                  int nbh) {
  if ((int)blockIdx.x < nbh) {
    int i = blockIdx.x * 256 + threadIdx.x;
    if (i < e) atomicAdd(&cnt[row[i]], 1);
  } else {
    int idx = (blockIdx.x - nbh) * 256 + threadIdx.x;   // 640*128 = 81920
    if (idx < 81920) {
      int c = idx >> 7, k = idx & 127;
      float w;
      if (c < 128)      w = Wq[k * 128 + c];
      else if (c < 512) w = Wkv[k * 384 + (c - 128)];
      else              w = Wvec[k * 128 + (c - 512)];
      Wt[idx] = (__bf16)w;
    }
  }
}

__global__ __launch_bounds__(1024) void scan1_kernel(const int* __restrict__ cnt, int* __restrict__ off,
                                                     int* __restrict__ bsum, int n) {
  __shared__ int sh[1024];
  int tid = threadIdx.x;
  int i = blockIdx.x * 1024 + tid;
  int v = (i < n) ? cnt[i] : 0;
  sh[tid] = v;
  __syncthreads();
  for (int d = 1; d < 1024; d <<= 1) {
    int t = (tid >= d) ? sh[tid - d] : 0;
    __syncthreads();
    sh[tid] += t;
    __syncthreads();
  }
  if (i < n) off[i] = sh[tid] - v;       // exclusive within block
  if (tid == 1023) bsum[blockIdx.x] = sh[1023];
}

// scan3 with folded block-prefix (scan2 eliminated)
__global__ __launch_bounds__(1024) void scan3_kernel(const int* __restrict__ bsum, int* __restrict__ off,
                                                     int* __restrict__ cursor, int n, int e) {
  __shared__ int base_sh;
  const int tid = threadIdx.x;
  if (tid < 64) {
    int part = 0;
    for (int b = tid; b < (int)blockIdx.x; b += 64) part += bsum[b];
    #pragma unroll
    for (int m = 32; m >= 1; m >>= 1) part += __shfl_xor(part, m);
    if (tid == 0) base_sh = part;
  }
  __syncthreads();
  const int base = base_sh;
  int i = blockIdx.x * 1024 + tid;
  if (i < n) { int o = off[i] + base; off[i] = o; cursor[i] = o; }
  if (i == 0) off[n] = e;
}

__global__ void scatter_kernel(const int* __restrict__ row, const int* __restrict__ col,
                               int* __restrict__ cursor, int* __restrict__ scol, int e) {
  int i = blockIdx.x * 256 + threadIdx.x;
  if (i < e) { int r = row[i]; int pos = atomicAdd(&cursor[r], 1); scol[pos] = col[i]; }
}

// ---------------- GEMM1 (MFMA): 64 rows x one 128-col chunk per block ----------------
// blockIdx.y: 0 -> q (bf16), 1 -> k (bf16), 2 -> v_s (bf16), 3 -> P = v_v*v (bf16 x3)

__global__ __launch_bounds__(256) void gemm1_mfma(
    const float* __restrict__ s, const __bf16* __restrict__ Wtg,
    const float* __restrict__ bq, const float* __restrict__ bkv,
    const float* __restrict__ v,
    __bf16* __restrict__ qb, __bf16* __restrict__ nodebuf, int n)
{
  __shared__ __bf16 sA[64 * 136];
  __shared__ char uB[34816];                 // union: sB (bf16 [128][136]) / sO (f32 [64][132])
  __bf16* sB = (__bf16*)uB;
  float*  sO = (float*)uB;

  const int tid = threadIdx.x;
  const int y = blockIdx.y;
  const int n0 = blockIdx.x * 64;
  const int drow = tid >> 2, dseg = tid & 3;
  const int dgn = n0 + drow;

  { // stage s tile -> bf16 LDS
    float4 f[8];
    if (dgn < n) {
      #pragma unroll
      for (int i = 0; i < 8; i++)
        f[i] = *(const float4*)&s[(size_t)dgn * 128 + dseg * 32 + i * 4];
    } else {
      #pragma unroll
      for (int i = 0; i < 8; i++) f[i] = make_float4(0.f, 0.f, 0.f, 0.f);
    }
    #pragma unroll
    for (int i = 0; i < 4; i++) {
      bf16x8 pk;
      pk[0] = (__bf16)f[2*i].x;   pk[1] = (__bf16)f[2*i].y;
      pk[2] = (__bf16)f[2*i].z;   pk[3] = (__bf16)f[2*i].w;
      pk[4] = (__bf16)f[2*i+1].x; pk[5] = (__bf16)f[2*i+1].y;
      pk[6] = (__bf16)f[2*i+1].z; pk[7] = (__bf16)f[2*i+1].w;
      *(bf16x8*)&sA[drow * 136 + dseg * 32 + i * 8] = pk;
    }
  }
  { // stage W^T chunk y
    int row = tid >> 1, half = tid & 1;
    const __bf16* src = &Wtg[(size_t)(y * 128 + row) * 128 + half * 64];
    #pragma unroll
    for (int i = 0; i < 8; i++)
      *(bf16x8*)&sB[row * 136 + half * 64 + i * 8] = *(const bf16x8*)&src[i * 8];
  }
  __syncthreads();

  const int wave = tid >> 6, lane = tid & 63;
  const int lr = lane & 15, lg = lane >> 4;

  bf16x8 a[4];
  #pragma unroll
  for (int ks = 0; ks < 4; ks++)
    a[ks] = *(const bf16x8*)&sA[(wave * 16 + lr) * 136 + ks * 32 + lg * 8];

  f32x4 acc[8];
  #pragma unroll
  for (int cf = 0; cf < 8; cf++) {
    f32x4 c = {0.f, 0.f, 0.f, 0.f};
    #pragma unroll
    for (int ks = 0; ks < 4; ks++) {
      bf16x8 b = *(const bf16x8*)&sB[(cf * 16 + lr) * 136 + ks * 32 + lg * 8];
      c = __builtin_amdgcn_mfma_f32_16x16x32_bf16(a[ks], b, c, 0, 0, 0);
    }
    acc[cf] = c;
  }
  __syncthreads();

  #pragma unroll
  for (int cf = 0; cf < 8; cf++) {
    int cl = cf * 16 + lr;
    #pragma unroll
    for (int r = 0; r < 4; r++)
      sO[(wave * 16 + lg * 4 + r) * 132 + cl] = acc[cf][r];
  }
  __syncthreads();

  if (dgn < n) {
    if (y == 0) {
      #pragma unroll
      for (int i = 0; i < 4; i++) {
        int c0 = dseg * 32 + i * 8;
        bf16x8 pk;
        #pragma unroll
        for (int j = 0; j < 8; j++)
          pk[j] = (__bf16)(sO[drow * 132 + c0 + j] + bq[c0 + j]);
        *(bf16x8*)&qb[(size_t)dgn * 128 + c0] = pk;
      }
    } else if (y == 1 || y == 2) {
      const int boff = (y - 1) * 128;
      #pragma unroll
      for (int i = 0; i < 4; i++) {
        int c0 = dseg * 32 + i * 8;
        bf16x8 pk;
        #pragma unroll
        for (int j = 0; j < 8; j++)
          pk[j] = (__bf16)(sO[drow * 132 + c0 + j] + bkv[boff + c0 + j]);
        *(bf16x8*)&nodebuf[(size_t)dgn * 640 + boff + c0] = pk;
      }
    } else {
      float vv[32];
      #pragma unroll
      for (int j = 0; j < 32; j++)
        vv[j] = sO[drow * 132 + dseg * 32 + j] + bkv[256 + dseg * 32 + j];
      #pragma unroll
      for (int j3 = 0; j3 < 3; j3++) {
        #pragma unroll
        for (int i = 0; i < 4; i++) {
          int c0 = dseg * 32 + i * 8;
          float4 va = *(const float4*)&v[((size_t)dgn * 3 + j3) * 128 + c0];
          float4 vb = *(const float4*)&v[((size_t)dgn * 3 + j3) * 128 + c0 + 4];
          bf16x8 pk;
          pk[0] = (__bf16)(vv[i*8+0] * va.x); pk[1] = (__bf16)(vv[i*8+1] * va.y);
          pk[2] = (__bf16)(vv[i*8+2] * va.z); pk[3] = (__bf16)(vv[i*8+3] * va.w);
          pk[4] = (__bf16)(vv[i*8+4] * vb.x); pk[5] = (__bf16)(vv[i*8+5] * vb.y);
          pk[6] = (__bf16)(vv[i*8+6] * vb.z); pk[7] = (__bf16)(vv[i*8+7] * vb.w);
          *(bf16x8*)&nodebuf[(size_t)dgn * 640 + 256 + j3 * 128 + c0] = pk;
        }
      }
    }
  }
}

// ---------------- Aggregation: 4 edges x 16 lanes, DPP reduce, DEPTH-2 prefetch ----------------

__device__ inline float2 bf2f(unsigned u) {
  float2 r;
  r.x = __uint_as_float((u & 0xffffu) << 16);
  r.y = __uint_as_float(u & 0xffff0000u);
  return r;
}

__device__ __forceinline__ float dpp_add(float x, const int ctrl) {
  int t;
  switch (ctrl) {
    case 0:  t = __builtin_amdgcn_update_dpp(0, __float_as_int(x), 0xB1, 0xF, 0xF, true); break;
    case 1:  t = __builtin_amdgcn_update_dpp(0, __float_as_int(x), 0x4E, 0xF, 0xF, true); break;
    case 2:  t = __builtin_amdgcn_update_dpp(0, __float_as_int(x), 0x141, 0xF, 0xF, true); break;
    default: t = __builtin_amdgcn_update_dpp(0, __float_as_int(x), 0x140, 0xF, 0xF, true); break;
  }
  return x + __int_as_float(t);
}

__device__ __forceinline__ float row16_sum(float x) {
  x = dpp_add(x, 0);
  x = dpp_add(x, 1);
  x = dpp_add(x, 2);
  x = dpp_add(x, 3);
  return x;
}

struct EdgeRegs { uint4 ku, vs, p0, p1, p2; };

__device__ __forceinline__ void issue_group(const char* __restrict__ nodebuf, int myc,
                                            int g, int cc, int slot, int fl, EdgeRegs& R) {
  int ei = g * 4 + slot;
  int c = __shfl(myc, (ei < cc) ? ei : (cc - 1));
  const char* gp = nodebuf + (size_t)c * 1280 + fl * 16;
  R.ku = *(const uint4*)(gp);
  R.vs = *(const uint4*)(gp + 256);
  R.p0 = *(const uint4*)(gp + 512);
  R.p1 = *(const uint4*)(gp + 768);
  R.p2 = *(const uint4*)(gp + 1024);
}

#define ACCP(arr, vec) do { float2 _t;                                                \
  _t = bf2f(vec.x); arr[0].x = fmaf(d, _t.x, arr[0].x); arr[0].y = fmaf(d, _t.y, arr[0].y); \
  _t = bf2f(vec.y); arr[1].x = fmaf(d, _t.x, arr[1].x); arr[1].y = fmaf(d, _t.y, arr[1].y); \
  _t = bf2f(vec.z); arr[2].x = fmaf(d, _t.x, arr[2].x); arr[2].y = fmaf(d, _t.y, arr[2].y); \
  _t = bf2f(vec.w); arr[3].x = fmaf(d, _t.x, arr[3].x); arr[3].y = fmaf(d, _t.y, arr[3].y); \
} while (0)

template<bool B16>
__global__ __launch_bounds__(256) void agg_kernel(
    const int* __restrict__ off, const int* __restrict__ scol,
    const __bf16* __restrict__ qb, const char* __restrict__ nodebuf,
    const float* __restrict__ s, float* __restrict__ s_out,
    float* __restrict__ aggvf, __bf16* __restrict__ aggv16, int n)
{
  const int wid = threadIdx.x >> 6;
  const int lane = threadIdx.x & 63;
  const int nid = blockIdx.x * 4 + wid;
  if (nid >= n) return;
  const int slot = lane >> 4;
  const int fl = lane & 15;

  float qf[8];
  {
    uint4 qu = *(const uint4*)&qb[(size_t)nid * 128 + fl * 8];
    float2 t;
    t = bf2f(qu.x); qf[0] = t.x; qf[1] = t.y;
    t = bf2f(qu.y); qf[2] = t.x; qf[3] = t.y;
    t = bf2f(qu.z); qf[4] = t.x; qf[5] = t.y;
    t = bf2f(qu.w); qf[6] = t.x; qf[7] = t.y;
  }

  float2 acs[4], a0[4], a1[4], a2[4];
  #pragma unroll
  for (int i = 0; i < 4; i++) {
    acs[i] = make_float2(0.f, 0.f); a0[i] = make_float2(0.f, 0.f);
    a1[i] = make_float2(0.f, 0.f); a2[i] = make_float2(0.f, 0.f);
  }

  const int beg = off[nid];
  const int deg = off[nid + 1] - beg;

  for (int chunk = 0; chunk < deg; chunk += 64) {
    const int cc = (deg - chunk < 64) ? (deg - chunk) : 64;
    int myc = (lane < cc) ? scol[beg + chunk + lane] : 0;
    const int ng = (cc + 3) >> 2;

    EdgeRegs A, B;
    issue_group(nodebuf, myc, 0, cc, slot, fl, A);
    if (ng > 1) issue_group(nodebuf, myc, 1, cc, slot, fl, B);

    #define COMPUTE(gidx, R) do {                                                  \
      float2 t; float d = 0.f;                                                     \
      t = bf2f(R.ku.x); d = fmaf(qf[0], t.x, d); d = fmaf(qf[1], t.y, d);          \
      t = bf2f(R.ku.y); d = fmaf(qf[2], t.x, d); d = fmaf(qf[3], t.y, d);          \
      t = bf2f(R.ku.z); d = fmaf(qf[4], t.x, d); d = fmaf(qf[5], t.y, d);          \
      t = bf2f(R.ku.w); d = fmaf(qf[6], t.x, d); d = fmaf(qf[7], t.y, d);          \
      d = row16_sum(d);                                                            \
      if ((gidx) * 4 + slot >= cc) d = 0.f;                                        \
      ACCP(acs, R.vs); ACCP(a0, R.p0); ACCP(a1, R.p1); ACCP(a2, R.p2);             \
    } while (0)

    int g = 0;
    for (; g + 1 < ng; g += 2) {
      COMPUTE(g, A);
      if (g + 2 < ng) issue_group(nodebuf, myc, g + 2, cc, slot, fl, A);
      COMPUTE(g + 1, B);
      if (g + 3 < ng) issue_group(nodebuf, myc, g + 3, cc, slot, fl, B);
    }
    if (g < ng) COMPUTE(g, A);
    #undef COMPUTE
  }

  // cross-slot reduction
  #pragma unroll
  for (int i = 0; i < 4; i++) {
    acs[i].x += __shfl_xor(acs[i].x, 16); acs[i].x += __shfl_xor(acs[i].x, 32);
    acs[i].y += __shfl_xor(acs[i].y, 16); acs[i].y += __shfl_xor(acs[i].y, 32);
    a0[i].x  += __shfl_xor(a0[i].x, 16);  a0[i].x  += __shfl_xor(a0[i].x, 32);
    a0[i].y  += __shfl_xor(a0[i].y, 16);  a0[i].y  += __shfl_xor(a0[i].y, 32);
    a1[i].x  += __shfl_xor(a1[i].x, 16);  a1[i].x  += __shfl_xor(a1[i].x, 32);
    a1[i].y  += __shfl_xor(a1[i].y, 16);  a1[i].y  += __shfl_xor(a1[i].y, 32);
    a2[i].x  += __shfl_xor(a2[i].x, 16);  a2[i].x  += __shfl_xor(a2[i].x, 32);
    a2[i].y  += __shfl_xor(a2[i].y, 16);  a2[i].y  += __shfl_xor(a2[i].y, 32);
  }

  if (slot == 0) {
    const float* sp = &s[(size_t)nid * 128 + fl * 8];
    float4 w0, w1;
    w0.x = acs[0].x + sp[0]; w0.y = acs[0].y + sp[1];
    w0.z = acs[1].x + sp[2]; w0.w = acs[1].y + sp[3];
    w1.x = acs[2].x + sp[4]; w1.y = acs[2].y + sp[5];
    w1.z = acs[3].x + sp[6]; w1.w = acs[3].y + sp[7];
    *(float4*)&s_out[(size_t)nid * 128 + fl * 8] = w0;
    *(float4*)&s_out[(size_t)nid * 128 + fl * 8 + 4] = w1;

    if (B16) {
      bf16x8 pk;
      pk[0] = (__bf16)a0[0].x; pk[1] = (__bf16)a0[0].y; pk[2] = (__bf16)a0[1].x; pk[3] = (__bf16)a0[1].y;
      pk[4] = (__bf16)a0[2].x; pk[5] = (__bf16)a0[2].y; pk[6] = (__bf16)a0[3].x; pk[7] = (__bf16)a0[3].y;
      *(bf16x8*)&aggv16[((size_t)nid * 3 + 0) * 128 + fl * 8] = pk;
      pk[0] = (__bf16)a1[0].x; pk[1] = (__bf16)a1[0].y; pk[2] = (__bf16)a1[1].x; pk[3] = (__bf16)a1[1].y;
      pk[4] = (__bf16)a1[2].x; pk[5] = (__bf16)a1[2].y; pk[6] = (__bf16)a1[3].x; pk[7] = (__bf16)a1[3].y;
      *(bf16x8*)&aggv16[((size_t)nid * 3 + 1) * 128 + fl * 8] = pk;
      pk[0] = (__bf16)a2[0].x; pk[1] = (__bf16)a2[0].y; pk[2] = (__bf16)a2[1].x; pk[3] = (__bf16)a2[1].y;
      pk[4] = (__bf16)a2[2].x; pk[5] = (__bf16)a2[2].y; pk[6] = (__bf16)a2[3].x; pk[7] = (__bf16)a2[3].y;
      *(bf16x8*)&aggv16[((size_t)nid * 3 + 2) * 128 + fl * 8] = pk;
    } else {
      float* av = &aggvf[(size_t)nid * 384 + fl * 8];
      *(float4*)&av[0]   = make_float4(a0[0].x, a0[0].y, a0[1].x, a0[1].y);
      *(float4*)&av[4]   = make_float4(a0[2].x, a0[2].y, a0[3].x, a0[3].y);
      *(float4*)&av[128] = make_float4(a1[0].x, a1[0].y, a1[1].x, a1[1].y);
      *(float4*)&av[132] = make_float4(a1[2].x, a1[2].y, a1[3].x, a1[3].y);
      *(float4*)&av[256] = make_float4(a2[0].x, a2[0].y, a2[1].x, a2[1].y);
      *(float4*)&av[260] = make_float4(a2[2].x, a2[2].y, a2[3].x, a2[3].y);
    }
  }
}

// ---------------- GEMM2 (MFMA, LDS-staged coalesced output): vout = v + aggv @ Wvec + bvec ----------------

template<bool B16>
__global__ __launch_bounds__(256) void gemm2_mfma(
    const __bf16* __restrict__ Wtg,   // rows 512..639 = Wvec^T
    const float* __restrict__ bvec, const float* __restrict__ v,
    const __bf16* __restrict__ aggv16, float* __restrict__ vout, int rows)
{
  __shared__ __bf16 sA[64 * 136];
  __shared__ char uB[34816];
  __bf16* sB = (__bf16*)uB;
  float*  sO = (float*)uB;

  const int tid = threadIdx.x;
  const int r0 = blockIdx.x * 64;
  const int drow = tid >> 2, dseg = tid & 3;
  const int dgr = r0 + drow;

  if (B16) {
    #pragma unroll
    for (int i = 0; i < 4; i++) {
      bf16x8 pk = {0,0,0,0,0,0,0,0};
      if (dgr < rows) pk = *(const bf16x8*)&aggv16[(size_t)dgr * 128 + dseg * 32 + i * 8];
      *(bf16x8*)&sA[drow * 136 + dseg * 32 + i * 8] = pk;
    }
  } else {
    float4 f[8];
    if (dgr < rows) {
      #pragma unroll
      for (int i = 0; i < 8; i++)
        f[i] = *(const float4*)&vout[(size_t)dgr * 128 + dseg * 32 + i * 4];
    } else {
      #pragma unroll
      for (int i = 0; i < 8; i++) f[i] = make_float4(0.f, 0.f, 0.f, 0.f);
    }
    #pragma unroll
    for (int i = 0; i < 4; i++) {
      bf16x8 pk;
      pk[0] = (__bf16)f[2*i].x;   pk[1] = (__bf16)f[2*i].y;
      pk[2] = (__bf16)f[2*i].z;   pk[3] = (__bf16)f[2*i].w;
      pk[4] = (__bf16)f[2*i+1].x; pk[5] = (__bf16)f[2*i+1].y;
      pk[6] = (__bf16)f[2*i+1].z; pk[7] = (__bf16)f[2*i+1].w;
      *(bf16x8*)&sA[drow * 136 + dseg * 32 + i * 8] = pk;
    }
  }
  { // stage Wvec^T
    int row = tid >> 1, half = tid & 1;
    const __bf16* src = &Wtg[(size_t)(512 + row) * 128 + half * 64];
    #pragma unroll
    for (int i = 0; i < 8; i++)
      *(bf16x8*)&sB[row * 136 + half * 64 + i * 8] = *(const bf16x8*)&src[i * 8];
  }
  __syncthreads();

  const int wave = tid >> 6, lane = tid & 63;
  const int lr = lane & 15, lg = lane >> 4;

  bf16x8 a[4];
  #pragma unroll
  for (int ks = 0; ks < 4; ks++)
    a[ks] = *(const bf16x8*)&sA[(wave * 16 + lr) * 136 + ks * 32 + lg * 8];

  f32x4 acc[8];
  #pragma unroll
  for (int cf = 0; cf < 8; cf++) {
    f32x4 c = {0.f, 0.f, 0.f, 0.f};
    #pragma unroll
    for (int ks = 0; ks < 4; ks++) {
      bf16x8 b = *(const bf16x8*)&sB[(cf * 16 + lr) * 136 + ks * 32 + lg * 8];
      c = __builtin_amdgcn_mfma_f32_16x16x32_bf16(a[ks], b, c, 0, 0, 0);
    }
    acc[cf] = c;
  }
  __syncthreads();

  #pragma unroll
  for (int cf = 0; cf < 8; cf++) {
    int cl = cf * 16 + lr;
    #pragma unroll
    for (int r = 0; r < 4; r++)
      sO[(wave * 16 + lg * 4 + r) * 132 + cl] = acc[cf][r];
  }
  __syncthreads();

  if (dgr < rows) {
    #pragma unroll
    for (int i = 0; i < 8; i++) {
      int c0 = dseg * 32 + i * 4;
      float4 va = *(const float4*)&v[(size_t)dgr * 128 + c0];
      float4 o;
      o.x = sO[drow * 132 + c0 + 0] + va.x + bvec[c0 + 0];
      o.y = sO[drow * 132 + c0 + 1] + va.y + bvec[c0 + 1];
      o.z = sO[drow * 132 + c0 + 2] + va.z + bvec[c0 + 2];
      o.w = sO[drow * 132 + c0 + 3] + va.w + bvec[c0 + 3];
      *(float4*)&vout[(size_t)dgr * 128 + c0] = o;
    }
  }
}

// ---------------- launch ----------------

extern "C" void kernel_launch(void* const* d_in, const int* in_sizes, int n_in,
                              void* d_out, int out_size, void* d_ws, size_t ws_size,
                              hipStream_t stream)
{
  const float* s    = (const float*)d_in[0];
  const float* v    = (const float*)d_in[1];
  const int*   ei   = (const int*)d_in[2];
  const float* Wq   = (const float*)d_in[3];
  const float* bq   = (const float*)d_in[4];
  const float* Wkv  = (const float*)d_in[5];
  const float* bkv  = (const float*)d_in[6];
  const float* Wvec = (const float*)d_in[7];
  const float* bvec = (const float*)d_in[8];

  const int N = in_sizes[0] / 128;
  const int E = in_sizes[2] / 2;
  const int* row = ei;
  const int* col = ei + E;

  char* ws = (char*)d_ws;
  size_t o = 0;
  auto alloc = [&](size_t bytes) -> char* {
    char* p = ws + o;
    o = (o + bytes + 255) & ~(size_t)255;
    return p;
  };
  int* off    = (int*)alloc((size_t)(N + 1) * 4);
  int* cursor = (int*)alloc((size_t)N * 4);
  int* bsum   = (int*)alloc(4096);
  int* scol   = (int*)alloc((size_t)E * 4);
  __bf16* qb      = (__bf16*)alloc((size_t)N * 128 * 2);
  __bf16* nodebuf = (__bf16*)alloc((size_t)N * 640 * 2);
  __bf16* Wt      = (__bf16*)alloc((size_t)640 * 128 * 2);
  __bf16* aggv16  = (__bf16*)alloc((size_t)N * 384 * 2);
  const bool b16 = (o <= ws_size);

  float* s_out = (float*)d_out;
  float* aggv  = (float*)d_out + (size_t)N * 128;

  // CSR build + W prep
  hipMemsetAsync(cursor, 0, (size_t)N * 4, stream);
  int nbh = (E + 255) / 256;
  hist_wprep_kernel<<<nbh + 320, 256, 0, stream>>>(row, cursor, E, Wq, Wkv, Wvec, Wt, nbh);
  int nb = (N + 1023) / 1024;
  scan1_kernel<<<nb, 1024, 0, stream>>>(cursor, off, bsum, N);
  scan3_kernel<<<nb, 1024, 0, stream>>>(bsum, off, cursor, N, E);
  scatter_kernel<<<(E + 255) / 256, 256, 0, stream>>>(row, col, cursor, scol, E);

  // node features
  dim3 g1((N + 63) / 64, 4);
  gemm1_mfma<<<g1, 256, 0, stream>>>(s, Wt, bq, bkv, v, qb, nodebuf, N);

  // edge aggregation (depth-2 prefetch)
  if (b16)
    agg_kernel<true><<<(N + 3) / 4, 256, 0, stream>>>(off, scol, qb, (const char*)nodebuf,
                                                      s, s_out, aggv, aggv16, N);
  else
    agg_kernel<false><<<(N + 3) / 4, 256, 0, stream>>>(off, scol, qb, (const char*)nodebuf,
                                                       s, s_out, aggv, aggv16, N);

  // v_out GEMM
  if (b16)
    gemm2_mfma<true><<<(3 * N + 63) / 64, 256, 0, stream>>>(Wt, bvec, v, aggv16, aggv, 3 * N);
  else
    gemm2_mfma<false><<<(3 * N + 63) / 64, 256, 0, stream>>>(Wt, bvec, v, aggv16, aggv, 3 * N);
}

// Round 10
// 299.011 us; speedup vs baseline: 1.5897x; 1.0399x over previous
//
#include <hip/hip_runtime.h>
#include <hip/hip_bf16.h>

typedef __attribute__((ext_vector_type(8))) __bf16 bf16x8;
typedef __attribute__((ext_vector_type(4))) float f32x4;

// ---------------- CSR hist + W prep + M prep (one kernel, disjoint block ranges) ----------------
// Wt layout [c][k], c in [0,640): 0..127 = M^T (qM weights), 128..511 = Wkv^T, 512..639 = Wvec^T

__global__ void prep_kernel(const int* __restrict__ row, int* __restrict__ cnt, int e,
                            const float* __restrict__ Wq, const float* __restrict__ Wkv,
                            const float* __restrict__ Wvec, const float* __restrict__ bq,
                            __bf16* __restrict__ Wt, float* __restrict__ bM,
                            float* __restrict__ m2, float* __restrict__ c0, int nbh) {
  const int bid = blockIdx.x, tid = threadIdx.x;
  if (bid < nbh) {                       // histogram
    int i = bid * 256 + tid;
    if (i < e) atomicAdd(&cnt[row[i]], 1);
  } else if (bid < nbh + 256) {          // transpose Wkv|Wvec -> Wt rows 128..639
    int idx = (bid - nbh) * 256 + tid;   // 512*128
    int c = 128 + (idx >> 7), k = idx & 127;
    float w = (c < 512) ? Wkv[k * 384 + (c - 128)] : Wvec[k * 128 + (c - 512)];
    Wt[c * 128 + k] = (__bf16)w;
  } else if (bid < nbh + 256 + 128) {    // M^T row c: Wt[c][t] = sum_j Wq[t,j]*Wk[c,j]
    __shared__ float wk[128];
    int c = bid - (nbh + 256);
    if (tid < 128) wk[tid] = Wkv[tid * 0 + c * 384 + tid];   // Wk[c,j] = Wkv[c*384+j]
    __syncthreads();
    if (tid < 128) {
      float acc = 0.f;
      #pragma unroll 8
      for (int j = 0; j < 128; j++) acc += Wq[tid * 128 + j] * wk[j];
      Wt[c * 128 + tid] = (__bf16)acc;
    } else if (tid == 128) {
      float acc = 0.f;
      for (int j = 0; j < 128; j++) acc += bq[j] * wk[j];
      bM[c] = acc;                        // bq @ Wk^T
    }
  } else {                               // m2 = Wq @ bk ; c0 = bq . bk   (bk = bkv[0:128])
    // handled in launch via bkv pointer passed in m2's own kernel arg c0 path below
  }
}

__global__ void m2_kernel(const float* __restrict__ Wq, const float* __restrict__ bq,
                          const float* __restrict__ bkv, float* __restrict__ m2,
                          float* __restrict__ c0) {
  int tid = threadIdx.x;
  if (tid < 128) {
    float acc = 0.f;
    for (int j = 0; j < 128; j++) acc += Wq[tid * 128 + j] * bkv[j];
    m2[tid] = acc;
  } else if (tid == 128) {
    float acc = 0.f;
    for (int j = 0; j < 128; j++) acc += bq[j] * bkv[j];
    c0[0] = acc;
  }
}

__global__ __launch_bounds__(1024) void scan1_kernel(const int* __restrict__ cnt, int* __restrict__ off,
                                                     int* __restrict__ bsum, int n) {
  __shared__ int sh[1024];
  int tid = threadIdx.x;
  int i = blockIdx.x * 1024 + tid;
  int v = (i < n) ? cnt[i] : 0;
  sh[tid] = v;
  __syncthreads();
  for (int d = 1; d < 1024; d <<= 1) {
    int t = (tid >= d) ? sh[tid - d] : 0;
    __syncthreads();
    sh[tid] += t;
    __syncthreads();
  }
  if (i < n) off[i] = sh[tid] - v;
  if (tid == 1023) bsum[blockIdx.x] = sh[1023];
}

__global__ __launch_bounds__(1024) void scan3_kernel(const int* __restrict__ bsum, int* __restrict__ off,
                                                     int* __restrict__ cursor, int n, int e) {
  __shared__ int base_sh;
  const int tid = threadIdx.x;
  if (tid < 64) {
    int part = 0;
    for (int b = tid; b < (int)blockIdx.x; b += 64) part += bsum[b];
    #pragma unroll
    for (int m = 32; m >= 1; m >>= 1) part += __shfl_xor(part, m);
    if (tid == 0) base_sh = part;
  }
  __syncthreads();
  const int base = base_sh;
  int i = blockIdx.x * 1024 + tid;
  if (i < n) { int o = off[i] + base; off[i] = o; cursor[i] = o; }
  if (i == 0) off[n] = e;
}

__global__ void scatter_kernel(const int* __restrict__ row, const int* __restrict__ col,
                               int* __restrict__ cursor, int* __restrict__ scol, int e) {
  int i = blockIdx.x * 256 + threadIdx.x;
  if (i < e) { int r = row[i]; int pos = atomicAdd(&cursor[r], 1); scol[pos] = col[i]; }
}

// ---------------- GEMM1 (MFMA): y=0 -> qM (+beta), y=1 -> P = (s@Wvv+bvv)*v and sbf ----------------
// nodebuf2 per node: [ sbf(128) | P0(128) | P1(128) | P2(128) ] bf16 = 1024 B

__global__ __launch_bounds__(256) void gemm1_mfma(
    const float* __restrict__ s, const __bf16* __restrict__ Wtg,
    const float* __restrict__ bM, const float* __restrict__ bkv,
    const float* __restrict__ m2, const float* __restrict__ c0,
    const float* __restrict__ v,
    __bf16* __restrict__ qb, float* __restrict__ beta,
    __bf16* __restrict__ nodebuf, int n)
{
  __shared__ __bf16 sA[64 * 136];
  __shared__ char uB[34816];                 // union: sB (bf16[128][136]) / sO (f32[64][132])
  __shared__ float sBeta[64][4];
  __bf16* sB = (__bf16*)uB;
  float*  sO = (float*)uB;

  const int tid = threadIdx.x;
  const int y = blockIdx.y;
  const int n0 = blockIdx.x * 64;
  const int drow = tid >> 2, dseg = tid & 3;
  const int dgn = n0 + drow;

  { // stage s tile -> bf16 LDS
    float4 f[8];
    if (dgn < n) {
      #pragma unroll
      for (int i = 0; i < 8; i++)
        f[i] = *(const float4*)&s[(size_t)dgn * 128 + dseg * 32 + i * 4];
    } else {
      #pragma unroll
      for (int i = 0; i < 8; i++) f[i] = make_float4(0.f, 0.f, 0.f, 0.f);
    }
    #pragma unroll
    for (int i = 0; i < 4; i++) {
      bf16x8 pk;
      pk[0] = (__bf16)f[2*i].x;   pk[1] = (__bf16)f[2*i].y;
      pk[2] = (__bf16)f[2*i].z;   pk[3] = (__bf16)f[2*i].w;
      pk[4] = (__bf16)f[2*i+1].x; pk[5] = (__bf16)f[2*i+1].y;
      pk[6] = (__bf16)f[2*i+1].z; pk[7] = (__bf16)f[2*i+1].w;
      *(bf16x8*)&sA[drow * 136 + dseg * 32 + i * 8] = pk;
    }
  }
  { // stage W^T chunk: y=0 -> rows 0..127 (M^T), y=1 -> rows 384..511 (Wvv^T)
    int row = tid >> 1, half = tid & 1;
    int brow = (y == 0) ? row : 384 + row;
    const __bf16* src = &Wtg[(size_t)brow * 128 + half * 64];
    #pragma unroll
    for (int i = 0; i < 8; i++)
      *(bf16x8*)&sB[row * 136 + half * 64 + i * 8] = *(const bf16x8*)&src[i * 8];
  }
  __syncthreads();

  const int wave = tid >> 6, lane = tid & 63;
  const int lr = lane & 15, lg = lane >> 4;

  bf16x8 a[4];
  #pragma unroll
  for (int ks = 0; ks < 4; ks++)
    a[ks] = *(const bf16x8*)&sA[(wave * 16 + lr) * 136 + ks * 32 + lg * 8];

  f32x4 acc[8];
  #pragma unroll
  for (int cf = 0; cf < 8; cf++) {
    f32x4 c = {0.f, 0.f, 0.f, 0.f};
    #pragma unroll
    for (int ks = 0; ks < 4; ks++) {
      bf16x8 b = *(const bf16x8*)&sB[(cf * 16 + lr) * 136 + ks * 32 + lg * 8];
      c = __builtin_amdgcn_mfma_f32_16x16x32_bf16(a[ks], b, c, 0, 0, 0);
    }
    acc[cf] = c;
  }
  __syncthreads();

  #pragma unroll
  for (int cf = 0; cf < 8; cf++) {
    int cl = cf * 16 + lr;
    #pragma unroll
    for (int r = 0; r < 4; r++)
      sO[(wave * 16 + lg * 4 + r) * 132 + cl] = acc[cf][r];
  }
  __syncthreads();

  if (y == 0) {
    // beta partials from sA (bf16 s) . m2
    float part = 0.f;
    #pragma unroll 8
    for (int j = 0; j < 32; j++)
      part += (float)sA[drow * 136 + dseg * 32 + j] * m2[dseg * 32 + j];
    sBeta[drow][dseg] = part;
    __syncthreads();
    if (dgn < n) {
      if (dseg == 0)
        beta[dgn] = sBeta[drow][0] + sBeta[drow][1] + sBeta[drow][2] + sBeta[drow][3] + c0[0];
      #pragma unroll
      for (int i = 0; i < 4; i++) {
        int cc = dseg * 32 + i * 8;
        bf16x8 pk;
        #pragma unroll
        for (int j = 0; j < 8; j++)
          pk[j] = (__bf16)(sO[drow * 132 + cc + j] + bM[cc + j]);
        *(bf16x8*)&qb[(size_t)dgn * 128 + cc] = pk;
      }
    }
  } else if (dgn < n) {
    // sbf copy from sA
    #pragma unroll
    for (int i = 0; i < 4; i++) {
      int cc = dseg * 32 + i * 8;
      *(bf16x8*)&nodebuf[(size_t)dgn * 512 + cc] = *(const bf16x8*)&sA[drow * 136 + cc];
    }
    // P = (s@Wvv + bvv) * v
    float vv[32];
    #pragma unroll
    for (int j = 0; j < 32; j++)
      vv[j] = sO[drow * 132 + dseg * 32 + j] + bkv[256 + dseg * 32 + j];
    #pragma unroll
    for (int j3 = 0; j3 < 3; j3++) {
      #pragma unroll
      for (int i = 0; i < 4; i++) {
        int cc = dseg * 32 + i * 8;
        float4 va = *(const float4*)&v[((size_t)dgn * 3 + j3) * 128 + cc];
        float4 vb = *(const float4*)&v[((size_t)dgn * 3 + j3) * 128 + cc + 4];
        bf16x8 pk;
        pk[0] = (__bf16)(vv[i*8+0] * va.x); pk[1] = (__bf16)(vv[i*8+1] * va.y);
        pk[2] = (__bf16)(vv[i*8+2] * va.z); pk[3] = (__bf16)(vv[i*8+3] * va.w);
        pk[4] = (__bf16)(vv[i*8+4] * vb.x); pk[5] = (__bf16)(vv[i*8+5] * vb.y);
        pk[6] = (__bf16)(vv[i*8+6] * vb.z); pk[7] = (__bf16)(vv[i*8+7] * vb.w);
        *(bf16x8*)&nodebuf[(size_t)dgn * 512 + 128 + j3 * 128 + cc] = pk;
      }
    }
  }
}

// ---------------- Aggregation: gather s[c]+P[c], w = qM.s[c]+beta, g/W1/aggv accumulate ----------------

__device__ inline float2 bf2f(unsigned u) {
  float2 r;
  r.x = __uint_as_float((u & 0xffffu) << 16);
  r.y = __uint_as_float(u & 0xffff0000u);
  return r;
}

__device__ __forceinline__ float dpp_add(float x, const int ctrl) {
  int t;
  switch (ctrl) {
    case 0:  t = __builtin_amdgcn_update_dpp(0, __float_as_int(x), 0xB1, 0xF, 0xF, true); break;
    case 1:  t = __builtin_amdgcn_update_dpp(0, __float_as_int(x), 0x4E, 0xF, 0xF, true); break;
    case 2:  t = __builtin_amdgcn_update_dpp(0, __float_as_int(x), 0x141, 0xF, 0xF, true); break;
    default: t = __builtin_amdgcn_update_dpp(0, __float_as_int(x), 0x140, 0xF, 0xF, true); break;
  }
  return x + __int_as_float(t);
}

__device__ __forceinline__ float row16_sum(float x) {
  x = dpp_add(x, 0); x = dpp_add(x, 1); x = dpp_add(x, 2); x = dpp_add(x, 3);
  return x;
}

#define ACCP(arr, vec) do { float2 _t;                                                \
  _t = bf2f(vec.x); arr[0].x = fmaf(d, _t.x, arr[0].x); arr[0].y = fmaf(d, _t.y, arr[0].y); \
  _t = bf2f(vec.y); arr[1].x = fmaf(d, _t.x, arr[1].x); arr[1].y = fmaf(d, _t.y, arr[1].y); \
  _t = bf2f(vec.z); arr[2].x = fmaf(d, _t.x, arr[2].x); arr[2].y = fmaf(d, _t.y, arr[2].y); \
  _t = bf2f(vec.w); arr[3].x = fmaf(d, _t.x, arr[3].x); arr[3].y = fmaf(d, _t.y, arr[3].y); \
} while (0)

__global__ __launch_bounds__(256) void agg_kernel(
    const int* __restrict__ off, const int* __restrict__ scol,
    const __bf16* __restrict__ qb, const float* __restrict__ beta,
    const char* __restrict__ nodebuf,
    __bf16* __restrict__ gb, float* __restrict__ W1,
    __bf16* __restrict__ aggv16, int n)
{
  const int wid = threadIdx.x >> 6;
  const int lane = threadIdx.x & 63;
  const int nid = blockIdx.x * 4 + wid;
  if (nid >= n) return;
  const int slot = lane >> 4;
  const int fl = lane & 15;

  float qf[8];
  {
    uint4 qu = *(const uint4*)&qb[(size_t)nid * 128 + fl * 8];
    float2 t;
    t = bf2f(qu.x); qf[0] = t.x; qf[1] = t.y;
    t = bf2f(qu.y); qf[2] = t.x; qf[3] = t.y;
    t = bf2f(qu.z); qf[4] = t.x; qf[5] = t.y;
    t = bf2f(qu.w); qf[6] = t.x; qf[7] = t.y;
  }
  const float betar = beta[nid];

  float2 g[4], a0[4], a1[4], a2[4];
  float ws = 0.f;
  #pragma unroll
  for (int i = 0; i < 4; i++) {
    g[i] = make_float2(0.f, 0.f); a0[i] = make_float2(0.f, 0.f);
    a1[i] = make_float2(0.f, 0.f); a2[i] = make_float2(0.f, 0.f);
  }

  const int beg = off[nid];
  const int deg = off[nid + 1] - beg;

  for (int chunk = 0; chunk < deg; chunk += 64) {
    const int cc = (deg - chunk < 64) ? (deg - chunk) : 64;
    int myc = (lane < cc) ? scol[beg + chunk + lane] : 0;

    int c0i = __shfl(myc, (slot < cc) ? slot : 0);
    const char* gp = nodebuf + (size_t)c0i * 1024 + fl * 16;
    uint4 sc = *(const uint4*)(gp);
    uint4 p0 = *(const uint4*)(gp + 256);
    uint4 p1 = *(const uint4*)(gp + 512);
    uint4 p2 = *(const uint4*)(gp + 768);

    for (int j = 0; j < cc; j += 4) {
      const bool more = (j + 4 < cc);
      uint4 nsc, np0, np1, np2;
      if (more) {
        int ni = j + 4 + slot;
        int cn = __shfl(myc, (ni < cc) ? ni : 0);
        const char* gn = nodebuf + (size_t)cn * 1024 + fl * 16;
        nsc = *(const uint4*)(gn);
        np0 = *(const uint4*)(gn + 256);
        np1 = *(const uint4*)(gn + 512);
        np2 = *(const uint4*)(gn + 768);
      }

      float2 t0 = bf2f(sc.x), t1 = bf2f(sc.y), t2 = bf2f(sc.z), t3 = bf2f(sc.w);
      float d = 0.f;
      d = fmaf(qf[0], t0.x, d); d = fmaf(qf[1], t0.y, d);
      d = fmaf(qf[2], t1.x, d); d = fmaf(qf[3], t1.y, d);
      d = fmaf(qf[4], t2.x, d); d = fmaf(qf[5], t2.y, d);
      d = fmaf(qf[6], t3.x, d); d = fmaf(qf[7], t3.y, d);
      d = row16_sum(d) + betar;
      if (j + slot >= cc) d = 0.f;

      // g += w * s[c]  (reuse unpacked regs)
      g[0].x = fmaf(d, t0.x, g[0].x); g[0].y = fmaf(d, t0.y, g[0].y);
      g[1].x = fmaf(d, t1.x, g[1].x); g[1].y = fmaf(d, t1.y, g[1].y);
      g[2].x = fmaf(d, t2.x, g[2].x); g[2].y = fmaf(d, t2.y, g[2].y);
      g[3].x = fmaf(d, t3.x, g[3].x); g[3].y = fmaf(d, t3.y, g[3].y);
      ws += d;
      ACCP(a0, p0); ACCP(a1, p1); ACCP(a2, p2);

      if (more) { sc = nsc; p0 = np0; p1 = np1; p2 = np2; }
    }
  }

  // cross-slot reduction
  ws += __shfl_xor(ws, 16); ws += __shfl_xor(ws, 32);
  #pragma unroll
  for (int i = 0; i < 4; i++) {
    g[i].x  += __shfl_xor(g[i].x, 16);  g[i].x  += __shfl_xor(g[i].x, 32);
    g[i].y  += __shfl_xor(g[i].y, 16);  g[i].y  += __shfl_xor(g[i].y, 32);
    a0[i].x += __shfl_xor(a0[i].x, 16); a0[i].x += __shfl_xor(a0[i].x, 32);
    a0[i].y += __shfl_xor(a0[i].y, 16); a0[i].y += __shfl_xor(a0[i].y, 32);
    a1[i].x += __shfl_xor(a1[i].x, 16); a1[i].x += __shfl_xor(a1[i].x, 32);
    a1[i].y += __shfl_xor(a1[i].y, 16); a1[i].y += __shfl_xor(a1[i].y, 32);
    a2[i].x += __shfl_xor(a2[i].x, 16); a2[i].x += __shfl_xor(a2[i].x, 32);
    a2[i].y += __shfl_xor(a2[i].y, 16); a2[i].y += __shfl_xor(a2[i].y, 32);
  }

  if (slot == 0) {
    bf16x8 pk;
    pk[0] = (__bf16)g[0].x; pk[1] = (__bf16)g[0].y; pk[2] = (__bf16)g[1].x; pk[3] = (__bf16)g[1].y;
    pk[4] = (__bf16)g[2].x; pk[5] = (__bf16)g[2].y; pk[6] = (__bf16)g[3].x; pk[7] = (__bf16)g[3].y;
    *(bf16x8*)&gb[(size_t)nid * 128 + fl * 8] = pk;
    if (fl == 0) W1[nid] = ws;

    pk[0] = (__bf16)a0[0].x; pk[1] = (__bf16)a0[0].y; pk[2] = (__bf16)a0[1].x; pk[3] = (__bf16)a0[1].y;
    pk[4] = (__bf16)a0[2].x; pk[5] = (__bf16)a0[2].y; pk[6] = (__bf16)a0[3].x; pk[7] = (__bf16)a0[3].y;
    *(bf16x8*)&aggv16[((size_t)nid * 3 + 0) * 128 + fl * 8] = pk;
    pk[0] = (__bf16)a1[0].x; pk[1] = (__bf16)a1[0].y; pk[2] = (__bf16)a1[1].x; pk[3] = (__bf16)a1[1].y;
    pk[4] = (__bf16)a1[2].x; pk[5] = (__bf16)a1[2].y; pk[6] = (__bf16)a1[3].x; pk[7] = (__bf16)a1[3].y;
    *(bf16x8*)&aggv16[((size_t)nid * 3 + 1) * 128 + fl * 8] = pk;
    pk[0] = (__bf16)a2[0].x; pk[1] = (__bf16)a2[0].y; pk[2] = (__bf16)a2[1].x; pk[3] = (__bf16)a2[1].y;
    pk[4] = (__bf16)a2[2].x; pk[5] = (__bf16)a2[2].y; pk[6] = (__bf16)a2[3].x; pk[7] = (__bf16)a2[3].y;
    *(bf16x8*)&aggv16[((size_t)nid * 3 + 2) * 128 + fl * 8] = pk;
  }
}

// ---------------- GEMM23 (MFMA): s_out = g@Wvs + W1*bvs + s ; vout = aggv@Wvec + v + bvec ----------------

__global__ __launch_bounds__(256) void gemm23_mfma(
    const __bf16* __restrict__ Wtg, const float* __restrict__ bkv, const float* __restrict__ bvec,
    const float* __restrict__ s, const float* __restrict__ v,
    const __bf16* __restrict__ gb, const float* __restrict__ W1,
    const __bf16* __restrict__ aggv16,
    float* __restrict__ s_out, float* __restrict__ vout, int n, int nb1)
{
  __shared__ __bf16 sA[64 * 136];
  __shared__ char uB[34816];
  __bf16* sB = (__bf16*)uB;
  float*  sO = (float*)uB;

  const int tid = threadIdx.x;
  const bool smode = (int)blockIdx.x < nb1;
  const int r0 = smode ? blockIdx.x * 64 : (blockIdx.x - nb1) * 64;
  const int rows = smode ? n : 3 * n;
  const int drow = tid >> 2, dseg = tid & 3;
  const int dgr = r0 + drow;

  { // stage A tile (bf16 source)
    const __bf16* Asrc = smode ? gb : aggv16;
    #pragma unroll
    for (int i = 0; i < 4; i++) {
      bf16x8 pk = {0,0,0,0,0,0,0,0};
      if (dgr < rows) pk = *(const bf16x8*)&Asrc[(size_t)dgr * 128 + dseg * 32 + i * 8];
      *(bf16x8*)&sA[drow * 136 + dseg * 32 + i * 8] = pk;
    }
  }
  { // stage B: Wvs^T rows 256.. or Wvec^T rows 512..
    int row = tid >> 1, half = tid & 1;
    int brow = (smode ? 256 : 512) + row;
    const __bf16* src = &Wtg[(size_t)brow * 128 + half * 64];
    #pragma unroll
    for (int i = 0; i < 8; i++)
      *(bf16x8*)&sB[row * 136 + half * 64 + i * 8] = *(const bf16x8*)&src[i * 8];
  }
  __syncthreads();

  const int wave = tid >> 6, lane = tid & 63;
  const int lr = lane & 15, lg = lane >> 4;

  bf16x8 a[4];
  #pragma unroll
  for (int ks = 0; ks < 4; ks++)
    a[ks] = *(const bf16x8*)&sA[(wave * 16 + lr) * 136 + ks * 32 + lg * 8];

  f32x4 acc[8];
  #pragma unroll
  for (int cf = 0; cf < 8; cf++) {
    f32x4 c = {0.f, 0.f, 0.f, 0.f};
    #pragma unroll
    for (int ks = 0; ks < 4; ks++) {
      bf16x8 b = *(const bf16x8*)&sB[(cf * 16 + lr) * 136 + ks * 32 + lg * 8];
      c = __builtin_amdgcn_mfma_f32_16x16x32_bf16(a[ks], b, c, 0, 0, 0);
    }
    acc[cf] = c;
  }
  __syncthreads();

  #pragma unroll
  for (int cf = 0; cf < 8; cf++) {
    int cl = cf * 16 + lr;
    #pragma unroll
    for (int r = 0; r < 4; r++)
      sO[(wave * 16 + lg * 4 + r) * 132 + cl] = acc[cf][r];
  }
  __syncthreads();

  if (dgr < rows) {
    if (smode) {
      const float w1 = W1[dgr];
      #pragma unroll
      for (int i = 0; i < 8; i++) {
        int cc = dseg * 32 + i * 4;
        float4 sa = *(const float4*)&s[(size_t)dgr * 128 + cc];
        float4 o;
        o.x = sO[drow * 132 + cc + 0] + sa.x + w1 * bkv[128 + cc + 0];
        o.y = sO[drow * 132 + cc + 1] + sa.y + w1 * bkv[128 + cc + 1];
        o.z = sO[drow * 132 + cc + 2] + sa.z + w1 * bkv[128 + cc + 2];
        o.w = sO[drow * 132 + cc + 3] + sa.w + w1 * bkv[128 + cc + 3];
        *(float4*)&s_out[(size_t)dgr * 128 + cc] = o;
      }
    } else {
      #pragma unroll
      for (int i = 0; i < 8; i++) {
        int cc = dseg * 32 + i * 4;
        float4 va = *(const float4*)&v[(size_t)dgr * 128 + cc];
        float4 o;
        o.x = sO[drow * 132 + cc + 0] + va.x + bvec[cc + 0];
        o.y = sO[drow * 132 + cc + 1] + va.y + bvec[cc + 1];
        o.z = sO[drow * 132 + cc + 2] + va.z + bvec[cc + 2];
        o.w = sO[drow * 132 + cc + 3] + va.w + bvec[cc + 3];
        *(float4*)&vout[(size_t)dgr * 128 + cc] = o;
      }
    }
  }
}

// ---------------- launch ----------------

extern "C" void kernel_launch(void* const* d_in, const int* in_sizes, int n_in,
                              void* d_out, int out_size, void* d_ws, size_t ws_size,
                              hipStream_t stream)
{
  const float* s    = (const float*)d_in[0];
  const float* v    = (const float*)d_in[1];
  const int*   ei   = (const int*)d_in[2];
  const float* Wq   = (const float*)d_in[3];
  const float* bq   = (const float*)d_in[4];
  const float* Wkv  = (const float*)d_in[5];
  const float* bkv  = (const float*)d_in[6];
  const float* Wvec = (const float*)d_in[7];
  const float* bvec = (const float*)d_in[8];

  const int N = in_sizes[0] / 128;
  const int E = in_sizes[2] / 2;
  const int* row = ei;
  const int* col = ei + E;

  char* ws = (char*)d_ws;
  size_t o = 0;
  auto alloc = [&](size_t bytes) -> char* {
    char* p = ws + o;
    o = (o + bytes + 255) & ~(size_t)255;
    return p;
  };
  int* off    = (int*)alloc((size_t)(N + 1) * 4);
  int* cursor = (int*)alloc((size_t)N * 4);
  int* bsum   = (int*)alloc(4096);
  int* scol   = (int*)alloc((size_t)E * 4);
  __bf16* qb      = (__bf16*)alloc((size_t)N * 128 * 2);
  float*  beta    = (float*)alloc((size_t)N * 4);
  float*  W1      = (float*)alloc((size_t)N * 4);
  __bf16* nodebuf = (__bf16*)alloc((size_t)N * 512 * 2);
  __bf16* Wt      = (__bf16*)alloc((size_t)640 * 128 * 2);
  __bf16* aggv16  = (__bf16*)alloc((size_t)N * 384 * 2);
  __bf16* gb      = (__bf16*)alloc((size_t)N * 128 * 2);
  float*  bM      = (float*)alloc(512);
  float*  m2      = (float*)alloc(512);
  float*  c0      = (float*)alloc(256);

  float* s_out = (float*)d_out;
  float* vout  = (float*)d_out + (size_t)N * 128;

  // CSR hist + weight transpose + M prep
  hipMemsetAsync(cursor, 0, (size_t)N * 4, stream);
  int nbh = (E + 255) / 256;
  prep_kernel<<<nbh + 256 + 128, 256, 0, stream>>>(row, cursor, E, Wq, Wkv, Wvec, bq,
                                                   Wt, bM, m2, c0, nbh);
  m2_kernel<<<1, 256, 0, stream>>>(Wq, bq, bkv, m2, c0);
  int nb = (N + 1023) / 1024;
  scan1_kernel<<<nb, 1024, 0, stream>>>(cursor, off, bsum, N);
  scan3_kernel<<<nb, 1024, 0, stream>>>(bsum, off, cursor, N, E);
  scatter_kernel<<<(E + 255) / 256, 256, 0, stream>>>(row, col, cursor, scol, E);

  // node features: qM (+beta) and sbf|P
  dim3 g1((N + 63) / 64, 2);
  gemm1_mfma<<<g1, 256, 0, stream>>>(s, Wt, bM, bkv, m2, c0, v, qb, beta, nodebuf, N);

  // edge aggregation
  agg_kernel<<<(N + 3) / 4, 256, 0, stream>>>(off, scol, qb, beta, (const char*)nodebuf,
                                              gb, W1, aggv16, N);

  // fused output GEMMs
  int nb1 = (N + 63) / 64;
  int nb2 = (3 * N + 63) / 64;
  gemm23_mfma<<<nb1 + nb2, 256, 0, stream>>>(Wt, bkv, bvec, s, v, gb, W1, aggv16,
                                             s_out, vout, N, nb1);
}

// Round 11
// 284.745 us; speedup vs baseline: 1.6694x; 1.0501x over previous
//
#include <hip/hip_runtime.h>
#include <hip/hip_bf16.h>

typedef __attribute__((ext_vector_type(8))) __bf16 bf16x8;
typedef __attribute__((ext_vector_type(4))) float f32x4;

// ---------------- prep: hist + W transpose + M^T/bM + m2/c0 (disjoint block ranges) ----------------
// Wt layout [c][k], c in [0,640): 0..127 = M^T, 128..511 = Wkv^T, 512..639 = Wvec^T

__global__ void prep_kernel(const int* __restrict__ row, int* __restrict__ cnt, int e,
                            const float* __restrict__ Wq, const float* __restrict__ Wkv,
                            const float* __restrict__ Wvec, const float* __restrict__ bq,
                            const float* __restrict__ bkv,
                            __bf16* __restrict__ Wt, float* __restrict__ bM,
                            float* __restrict__ m2, float* __restrict__ c0, int nbh) {
  const int bid = blockIdx.x, tid = threadIdx.x;
  if (bid < nbh) {                       // histogram
    int i = bid * 256 + tid;
    if (i < e) atomicAdd(&cnt[row[i]], 1);
  } else if (bid < nbh + 256) {          // transpose Wkv|Wvec -> Wt rows 128..639
    int idx = (bid - nbh) * 256 + tid;   // 512*128
    int c = 128 + (idx >> 7), k = idx & 127;
    float w = (c < 512) ? Wkv[k * 384 + (c - 128)] : Wvec[k * 128 + (c - 512)];
    Wt[c * 128 + k] = (__bf16)w;
  } else if (bid < nbh + 256 + 128) {    // M^T row c: Wt[c][t] = sum_j Wq[t,j]*Wk[c,j]
    __shared__ float wk[128];
    int c = bid - (nbh + 256);
    if (tid < 128) wk[tid] = Wkv[c * 384 + tid];   // Wk[c,j]
    __syncthreads();
    if (tid < 128) {
      float acc = 0.f;
      #pragma unroll 8
      for (int j = 0; j < 128; j++) acc += Wq[tid * 128 + j] * wk[j];
      Wt[c * 128 + tid] = (__bf16)acc;
    } else if (tid == 128) {
      float acc = 0.f;
      for (int j = 0; j < 128; j++) acc += bq[j] * wk[j];
      bM[c] = acc;                        // bq @ Wk^T
    }
  } else {                               // m2 = Wq @ bk ; c0 = bq . bk
    if (tid < 128) {
      float acc = 0.f;
      for (int j = 0; j < 128; j++) acc += Wq[tid * 128 + j] * bkv[j];
      m2[tid] = acc;
    } else if (tid == 128) {
      float acc = 0.f;
      for (int j = 0; j < 128; j++) acc += bq[j] * bkv[j];
      c0[0] = acc;
    }
  }
}

__global__ __launch_bounds__(1024) void scan1_kernel(const int* __restrict__ cnt, int* __restrict__ off,
                                                     int* __restrict__ bsum, int n) {
  __shared__ int sh[1024];
  int tid = threadIdx.x;
  int i = blockIdx.x * 1024 + tid;
  int v = (i < n) ? cnt[i] : 0;
  sh[tid] = v;
  __syncthreads();
  for (int d = 1; d < 1024; d <<= 1) {
    int t = (tid >= d) ? sh[tid - d] : 0;
    __syncthreads();
    sh[tid] += t;
    __syncthreads();
  }
  if (i < n) off[i] = sh[tid] - v;
  if (tid == 1023) bsum[blockIdx.x] = sh[1023];
}

__global__ __launch_bounds__(1024) void scan3_kernel(const int* __restrict__ bsum, int* __restrict__ off,
                                                     int* __restrict__ cursor, int n, int e) {
  __shared__ int base_sh;
  const int tid = threadIdx.x;
  if (tid < 64) {
    int part = 0;
    for (int b = tid; b < (int)blockIdx.x; b += 64) part += bsum[b];
    #pragma unroll
    for (int m = 32; m >= 1; m >>= 1) part += __shfl_xor(part, m);
    if (tid == 0) base_sh = part;
  }
  __syncthreads();
  const int base = base_sh;
  int i = blockIdx.x * 1024 + tid;
  if (i < n) { int o = off[i] + base; off[i] = o; cursor[i] = o; }
  if (i == 0) off[n] = e;
}

// ---------------- scatter + GEMM1 merged (gemm1 blocks first, scatter fills in) ----------------
// gemm1 y=0 -> qM(+beta); y=1 -> sbf | P = (s@Wvv+bvv)*v.  nodebuf/node: [sbf|P0|P1|P2] bf16.

__global__ __launch_bounds__(256) void scatter_gemm1(
    const int* __restrict__ row, const int* __restrict__ col,
    int* __restrict__ cursor, int* __restrict__ scol, int e, int ngemm,
    const float* __restrict__ s, const __bf16* __restrict__ Wtg,
    const float* __restrict__ bM, const float* __restrict__ bkv,
    const float* __restrict__ m2, const float* __restrict__ c0,
    const float* __restrict__ v,
    __bf16* __restrict__ qb, float* __restrict__ beta,
    __bf16* __restrict__ nodebuf, int n)
{
  __shared__ __bf16 sA[64 * 136];
  __shared__ char uB[34816];                 // union: sB (bf16[128][136]) / sO (f32[64][132])
  __shared__ float sBeta[64][4];
  __bf16* sB = (__bf16*)uB;
  float*  sO = (float*)uB;

  const int tid = threadIdx.x;
  if ((int)blockIdx.x >= ngemm) {            // -------- scatter part --------
    int i = ((int)blockIdx.x - ngemm) * 256 + tid;
    if (i < e) { int r = row[i]; int pos = atomicAdd(&cursor[r], 1); scol[pos] = col[i]; }
    return;
  }

  // -------- gemm1 part --------
  const int nb1 = (n + 63) >> 6;
  const int y = ((int)blockIdx.x < nb1) ? 0 : 1;
  const int n0 = (y == 0 ? (int)blockIdx.x : (int)blockIdx.x - nb1) * 64;
  const int drow = tid >> 2, dseg = tid & 3;
  const int dgn = n0 + drow;

  { // stage s tile -> bf16 LDS
    float4 f[8];
    if (dgn < n) {
      #pragma unroll
      for (int i = 0; i < 8; i++)
        f[i] = *(const float4*)&s[(size_t)dgn * 128 + dseg * 32 + i * 4];
    } else {
      #pragma unroll
      for (int i = 0; i < 8; i++) f[i] = make_float4(0.f, 0.f, 0.f, 0.f);
    }
    #pragma unroll
    for (int i = 0; i < 4; i++) {
      bf16x8 pk;
      pk[0] = (__bf16)f[2*i].x;   pk[1] = (__bf16)f[2*i].y;
      pk[2] = (__bf16)f[2*i].z;   pk[3] = (__bf16)f[2*i].w;
      pk[4] = (__bf16)f[2*i+1].x; pk[5] = (__bf16)f[2*i+1].y;
      pk[6] = (__bf16)f[2*i+1].z; pk[7] = (__bf16)f[2*i+1].w;
      *(bf16x8*)&sA[drow * 136 + dseg * 32 + i * 8] = pk;
    }
  }
  { // stage W^T chunk: y=0 -> rows 0..127 (M^T), y=1 -> rows 384..511 (Wvv^T)
    int r2 = tid >> 1, half = tid & 1;
    int brow = (y == 0) ? r2 : 384 + r2;
    const __bf16* src = &Wtg[(size_t)brow * 128 + half * 64];
    #pragma unroll
    for (int i = 0; i < 8; i++)
      *(bf16x8*)&sB[r2 * 136 + half * 64 + i * 8] = *(const bf16x8*)&src[i * 8];
  }
  __syncthreads();

  const int wave = tid >> 6, lane = tid & 63;
  const int lr = lane & 15, lg = lane >> 4;

  bf16x8 a[4];
  #pragma unroll
  for (int ks = 0; ks < 4; ks++)
    a[ks] = *(const bf16x8*)&sA[(wave * 16 + lr) * 136 + ks * 32 + lg * 8];

  f32x4 acc[8];
  #pragma unroll
  for (int cf = 0; cf < 8; cf++) {
    f32x4 c = {0.f, 0.f, 0.f, 0.f};
    #pragma unroll
    for (int ks = 0; ks < 4; ks++) {
      bf16x8 b = *(const bf16x8*)&sB[(cf * 16 + lr) * 136 + ks * 32 + lg * 8];
      c = __builtin_amdgcn_mfma_f32_16x16x32_bf16(a[ks], b, c, 0, 0, 0);
    }
    acc[cf] = c;
  }
  __syncthreads();

  #pragma unroll
  for (int cf = 0; cf < 8; cf++) {
    int cl = cf * 16 + lr;
    #pragma unroll
    for (int r = 0; r < 4; r++)
      sO[(wave * 16 + lg * 4 + r) * 132 + cl] = acc[cf][r];
  }
  __syncthreads();

  if (y == 0) {
    float part = 0.f;
    #pragma unroll 8
    for (int j = 0; j < 32; j++)
      part += (float)sA[drow * 136 + dseg * 32 + j] * m2[dseg * 32 + j];
    sBeta[drow][dseg] = part;
    __syncthreads();
    if (dgn < n) {
      if (dseg == 0)
        beta[dgn] = sBeta[drow][0] + sBeta[drow][1] + sBeta[drow][2] + sBeta[drow][3] + c0[0];
      #pragma unroll
      for (int i = 0; i < 4; i++) {
        int cc = dseg * 32 + i * 8;
        bf16x8 pk;
        #pragma unroll
        for (int j = 0; j < 8; j++)
          pk[j] = (__bf16)(sO[drow * 132 + cc + j] + bM[cc + j]);
        *(bf16x8*)&qb[(size_t)dgn * 128 + cc] = pk;
      }
    }
  } else if (dgn < n) {
    #pragma unroll
    for (int i = 0; i < 4; i++) {
      int cc = dseg * 32 + i * 8;
      *(bf16x8*)&nodebuf[(size_t)dgn * 512 + cc] = *(const bf16x8*)&sA[drow * 136 + cc];
    }
    float vv[32];
    #pragma unroll
    for (int j = 0; j < 32; j++)
      vv[j] = sO[drow * 132 + dseg * 32 + j] + bkv[256 + dseg * 32 + j];
    #pragma unroll
    for (int j3 = 0; j3 < 3; j3++) {
      #pragma unroll
      for (int i = 0; i < 4; i++) {
        int cc = dseg * 32 + i * 8;
        float4 va = *(const float4*)&v[((size_t)dgn * 3 + j3) * 128 + cc];
        float4 vb = *(const float4*)&v[((size_t)dgn * 3 + j3) * 128 + cc + 4];
        bf16x8 pk;
        pk[0] = (__bf16)(vv[i*8+0] * va.x); pk[1] = (__bf16)(vv[i*8+1] * va.y);
        pk[2] = (__bf16)(vv[i*8+2] * va.z); pk[3] = (__bf16)(vv[i*8+3] * va.w);
        pk[4] = (__bf16)(vv[i*8+4] * vb.x); pk[5] = (__bf16)(vv[i*8+5] * vb.y);
        pk[6] = (__bf16)(vv[i*8+6] * vb.z); pk[7] = (__bf16)(vv[i*8+7] * vb.w);
        *(bf16x8*)&nodebuf[(size_t)dgn * 512 + 128 + j3 * 128 + cc] = pk;
      }
    }
  }
}

// ---------------- Aggregation (unchanged from r10): gather s[c]+P[c], DPP reduce ----------------

__device__ inline float2 bf2f(unsigned u) {
  float2 r;
  r.x = __uint_as_float((u & 0xffffu) << 16);
  r.y = __uint_as_float(u & 0xffff0000u);
  return r;
}

__device__ __forceinline__ float dpp_add(float x, const int ctrl) {
  int t;
  switch (ctrl) {
    case 0:  t = __builtin_amdgcn_update_dpp(0, __float_as_int(x), 0xB1, 0xF, 0xF, true); break;
    case 1:  t = __builtin_amdgcn_update_dpp(0, __float_as_int(x), 0x4E, 0xF, 0xF, true); break;
    case 2:  t = __builtin_amdgcn_update_dpp(0, __float_as_int(x), 0x141, 0xF, 0xF, true); break;
    default: t = __builtin_amdgcn_update_dpp(0, __float_as_int(x), 0x140, 0xF, 0xF, true); break;
  }
  return x + __int_as_float(t);
}

__device__ __forceinline__ float row16_sum(float x) {
  x = dpp_add(x, 0); x = dpp_add(x, 1); x = dpp_add(x, 2); x = dpp_add(x, 3);
  return x;
}

#define ACCP(arr, vec) do { float2 _t;                                                \
  _t = bf2f(vec.x); arr[0].x = fmaf(d, _t.x, arr[0].x); arr[0].y = fmaf(d, _t.y, arr[0].y); \
  _t = bf2f(vec.y); arr[1].x = fmaf(d, _t.x, arr[1].x); arr[1].y = fmaf(d, _t.y, arr[1].y); \
  _t = bf2f(vec.z); arr[2].x = fmaf(d, _t.x, arr[2].x); arr[2].y = fmaf(d, _t.y, arr[2].y); \
  _t = bf2f(vec.w); arr[3].x = fmaf(d, _t.x, arr[3].x); arr[3].y = fmaf(d, _t.y, arr[3].y); \
} while (0)

__global__ __launch_bounds__(256) void agg_kernel(
    const int* __restrict__ off, const int* __restrict__ scol,
    const __bf16* __restrict__ qb, const float* __restrict__ beta,
    const char* __restrict__ nodebuf,
    __bf16* __restrict__ gb, float* __restrict__ W1,
    __bf16* __restrict__ aggv16, int n)
{
  const int wid = threadIdx.x >> 6;
  const int lane = threadIdx.x & 63;
  const int nid = blockIdx.x * 4 + wid;
  if (nid >= n) return;
  const int slot = lane >> 4;
  const int fl = lane & 15;

  float qf[8];
  {
    uint4 qu = *(const uint4*)&qb[(size_t)nid * 128 + fl * 8];
    float2 t;
    t = bf2f(qu.x); qf[0] = t.x; qf[1] = t.y;
    t = bf2f(qu.y); qf[2] = t.x; qf[3] = t.y;
    t = bf2f(qu.z); qf[4] = t.x; qf[5] = t.y;
    t = bf2f(qu.w); qf[6] = t.x; qf[7] = t.y;
  }
  const float betar = beta[nid];

  float2 g[4], a0[4], a1[4], a2[4];
  float ws = 0.f;
  #pragma unroll
  for (int i = 0; i < 4; i++) {
    g[i] = make_float2(0.f, 0.f); a0[i] = make_float2(0.f, 0.f);
    a1[i] = make_float2(0.f, 0.f); a2[i] = make_float2(0.f, 0.f);
  }

  const int beg = off[nid];
  const int deg = off[nid + 1] - beg;

  for (int chunk = 0; chunk < deg; chunk += 64) {
    const int cc = (deg - chunk < 64) ? (deg - chunk) : 64;
    int myc = (lane < cc) ? scol[beg + chunk + lane] : 0;

    int c0i = __shfl(myc, (slot < cc) ? slot : 0);
    const char* gp = nodebuf + (size_t)c0i * 1024 + fl * 16;
    uint4 sc = *(const uint4*)(gp);
    uint4 p0 = *(const uint4*)(gp + 256);
    uint4 p1 = *(const uint4*)(gp + 512);
    uint4 p2 = *(const uint4*)(gp + 768);

    for (int j = 0; j < cc; j += 4) {
      const bool more = (j + 4 < cc);
      uint4 nsc, np0, np1, np2;
      if (more) {
        int ni = j + 4 + slot;
        int cn = __shfl(myc, (ni < cc) ? ni : 0);
        const char* gn = nodebuf + (size_t)cn * 1024 + fl * 16;
        nsc = *(const uint4*)(gn);
        np0 = *(const uint4*)(gn + 256);
        np1 = *(const uint4*)(gn + 512);
        np2 = *(const uint4*)(gn + 768);
      }

      float2 t0 = bf2f(sc.x), t1 = bf2f(sc.y), t2 = bf2f(sc.z), t3 = bf2f(sc.w);
      float d = 0.f;
      d = fmaf(qf[0], t0.x, d); d = fmaf(qf[1], t0.y, d);
      d = fmaf(qf[2], t1.x, d); d = fmaf(qf[3], t1.y, d);
      d = fmaf(qf[4], t2.x, d); d = fmaf(qf[5], t2.y, d);
      d = fmaf(qf[6], t3.x, d); d = fmaf(qf[7], t3.y, d);
      d = row16_sum(d) + betar;
      if (j + slot >= cc) d = 0.f;

      g[0].x = fmaf(d, t0.x, g[0].x); g[0].y = fmaf(d, t0.y, g[0].y);
      g[1].x = fmaf(d, t1.x, g[1].x); g[1].y = fmaf(d, t1.y, g[1].y);
      g[2].x = fmaf(d, t2.x, g[2].x); g[2].y = fmaf(d, t2.y, g[2].y);
      g[3].x = fmaf(d, t3.x, g[3].x); g[3].y = fmaf(d, t3.y, g[3].y);
      ws += d;
      ACCP(a0, p0); ACCP(a1, p1); ACCP(a2, p2);

      if (more) { sc = nsc; p0 = np0; p1 = np1; p2 = np2; }
    }
  }

  ws += __shfl_xor(ws, 16); ws += __shfl_xor(ws, 32);
  #pragma unroll
  for (int i = 0; i < 4; i++) {
    g[i].x  += __shfl_xor(g[i].x, 16);  g[i].x  += __shfl_xor(g[i].x, 32);
    g[i].y  += __shfl_xor(g[i].y, 16);  g[i].y  += __shfl_xor(g[i].y, 32);
    a0[i].x += __shfl_xor(a0[i].x, 16); a0[i].x += __shfl_xor(a0[i].x, 32);
    a0[i].y += __shfl_xor(a0[i].y, 16); a0[i].y += __shfl_xor(a0[i].y, 32);
    a1[i].x += __shfl_xor(a1[i].x, 16); a1[i].x += __shfl_xor(a1[i].x, 32);
    a1[i].y += __shfl_xor(a1[i].y, 16); a1[i].y += __shfl_xor(a1[i].y, 32);
    a2[i].x += __shfl_xor(a2[i].x, 16); a2[i].x += __shfl_xor(a2[i].x, 32);
    a2[i].y += __shfl_xor(a2[i].y, 16); a2[i].y += __shfl_xor(a2[i].y, 32);
  }

  if (slot == 0) {
    bf16x8 pk;
    pk[0] = (__bf16)g[0].x; pk[1] = (__bf16)g[0].y; pk[2] = (__bf16)g[1].x; pk[3] = (__bf16)g[1].y;
    pk[4] = (__bf16)g[2].x; pk[5] = (__bf16)g[2].y; pk[6] = (__bf16)g[3].x; pk[7] = (__bf16)g[3].y;
    *(bf16x8*)&gb[(size_t)nid * 128 + fl * 8] = pk;
    if (fl == 0) W1[nid] = ws;

    pk[0] = (__bf16)a0[0].x; pk[1] = (__bf16)a0[0].y; pk[2] = (__bf16)a0[1].x; pk[3] = (__bf16)a0[1].y;
    pk[4] = (__bf16)a0[2].x; pk[5] = (__bf16)a0[2].y; pk[6] = (__bf16)a0[3].x; pk[7] = (__bf16)a0[3].y;
    *(bf16x8*)&aggv16[((size_t)nid * 3 + 0) * 128 + fl * 8] = pk;
    pk[0] = (__bf16)a1[0].x; pk[1] = (__bf16)a1[0].y; pk[2] = (__bf16)a1[1].x; pk[3] = (__bf16)a1[1].y;
    pk[4] = (__bf16)a1[2].x; pk[5] = (__bf16)a1[2].y; pk[6] = (__bf16)a1[3].x; pk[7] = (__bf16)a1[3].y;
    *(bf16x8*)&aggv16[((size_t)nid * 3 + 1) * 128 + fl * 8] = pk;
    pk[0] = (__bf16)a2[0].x; pk[1] = (__bf16)a2[0].y; pk[2] = (__bf16)a2[1].x; pk[3] = (__bf16)a2[1].y;
    pk[4] = (__bf16)a2[2].x; pk[5] = (__bf16)a2[2].y; pk[6] = (__bf16)a2[3].x; pk[7] = (__bf16)a2[3].y;
    *(bf16x8*)&aggv16[((size_t)nid * 3 + 2) * 128 + fl * 8] = pk;
  }
}

// ---------------- GEMM23 (MFMA): s_out = g@Wvs + W1*bvs + s ; vout = aggv@Wvec + v + bvec ----------------

__global__ __launch_bounds__(256) void gemm23_mfma(
    const __bf16* __restrict__ Wtg, const float* __restrict__ bkv, const float* __restrict__ bvec,
    const float* __restrict__ s, const float* __restrict__ v,
    const __bf16* __restrict__ gb, const float* __restrict__ W1,
    const __bf16* __restrict__ aggv16,
    float* __restrict__ s_out, float* __restrict__ vout, int n, int nb1)
{
  __shared__ __bf16 sA[64 * 136];
  __shared__ char uB[34816];
  __bf16* sB = (__bf16*)uB;
  float*  sO = (float*)uB;

  const int tid = threadIdx.x;
  const bool smode = (int)blockIdx.x < nb1;
  const int r0 = smode ? blockIdx.x * 64 : (blockIdx.x - nb1) * 64;
  const int rows = smode ? n : 3 * n;
  const int drow = tid >> 2, dseg = tid & 3;
  const int dgr = r0 + drow;

  {
    const __bf16* Asrc = smode ? gb : aggv16;
    #pragma unroll
    for (int i = 0; i < 4; i++) {
      bf16x8 pk = {0,0,0,0,0,0,0,0};
      if (dgr < rows) pk = *(const bf16x8*)&Asrc[(size_t)dgr * 128 + dseg * 32 + i * 8];
      *(bf16x8*)&sA[drow * 136 + dseg * 32 + i * 8] = pk;
    }
  }
  {
    int r2 = tid >> 1, half = tid & 1;
    int brow = (smode ? 256 : 512) + r2;
    const __bf16* src = &Wtg[(size_t)brow * 128 + half * 64];
    #pragma unroll
    for (int i = 0; i < 8; i++)
      *(bf16x8*)&sB[r2 * 136 + half * 64 + i * 8] = *(const bf16x8*)&src[i * 8];
  }
  __syncthreads();

  const int wave = tid >> 6, lane = tid & 63;
  const int lr = lane & 15, lg = lane >> 4;

  bf16x8 a[4];
  #pragma unroll
  for (int ks = 0; ks < 4; ks++)
    a[ks] = *(const bf16x8*)&sA[(wave * 16 + lr) * 136 + ks * 32 + lg * 8];

  f32x4 acc[8];
  #pragma unroll
  for (int cf = 0; cf < 8; cf++) {
    f32x4 c = {0.f, 0.f, 0.f, 0.f};
    #pragma unroll
    for (int ks = 0; ks < 4; ks++) {
      bf16x8 b = *(const bf16x8*)&sB[(cf * 16 + lr) * 136 + ks * 32 + lg * 8];
      c = __builtin_amdgcn_mfma_f32_16x16x32_bf16(a[ks], b, c, 0, 0, 0);
    }
    acc[cf] = c;
  }
  __syncthreads();

  #pragma unroll
  for (int cf = 0; cf < 8; cf++) {
    int cl = cf * 16 + lr;
    #pragma unroll
    for (int r = 0; r < 4; r++)
      sO[(wave * 16 + lg * 4 + r) * 132 + cl] = acc[cf][r];
  }
  __syncthreads();

  if (dgr < rows) {
    if (smode) {
      const float w1 = W1[dgr];
      #pragma unroll
      for (int i = 0; i < 8; i++) {
        int cc = dseg * 32 + i * 4;
        float4 sa = *(const float4*)&s[(size_t)dgr * 128 + cc];
        float4 o;
        o.x = sO[drow * 132 + cc + 0] + sa.x + w1 * bkv[128 + cc + 0];
        o.y = sO[drow * 132 + cc + 1] + sa.y + w1 * bkv[128 + cc + 1];
        o.z = sO[drow * 132 + cc + 2] + sa.z + w1 * bkv[128 + cc + 2];
        o.w = sO[drow * 132 + cc + 3] + sa.w + w1 * bkv[128 + cc + 3];
        *(float4*)&s_out[(size_t)dgr * 128 + cc] = o;
      }
    } else {
      #pragma unroll
      for (int i = 0; i < 8; i++) {
        int cc = dseg * 32 + i * 4;
        float4 va = *(const float4*)&v[(size_t)dgr * 128 + cc];
        float4 o;
        o.x = sO[drow * 132 + cc + 0] + va.x + bvec[cc + 0];
        o.y = sO[drow * 132 + cc + 1] + va.y + bvec[cc + 1];
        o.z = sO[drow * 132 + cc + 2] + va.z + bvec[cc + 2];
        o.w = sO[drow * 132 + cc + 3] + va.w + bvec[cc + 3];
        *(float4*)&vout[(size_t)dgr * 128 + cc] = o;
      }
    }
  }
}

// ---------------- launch ----------------

extern "C" void kernel_launch(void* const* d_in, const int* in_sizes, int n_in,
                              void* d_out, int out_size, void* d_ws, size_t ws_size,
                              hipStream_t stream)
{
  const float* s    = (const float*)d_in[0];
  const float* v    = (const float*)d_in[1];
  const int*   ei   = (const int*)d_in[2];
  const float* Wq   = (const float*)d_in[3];
  const float* bq   = (const float*)d_in[4];
  const float* Wkv  = (const float*)d_in[5];
  const float* bkv  = (const float*)d_in[6];
  const float* Wvec = (const float*)d_in[7];
  const float* bvec = (const float*)d_in[8];

  const int N = in_sizes[0] / 128;
  const int E = in_sizes[2] / 2;
  const int* row = ei;
  const int* col = ei + E;

  char* ws = (char*)d_ws;
  size_t o = 0;
  auto alloc = [&](size_t bytes) -> char* {
    char* p = ws + o;
    o = (o + bytes + 255) & ~(size_t)255;
    return p;
  };
  int* off    = (int*)alloc((size_t)(N + 1) * 4);
  int* cursor = (int*)alloc((size_t)N * 4);
  int* bsum   = (int*)alloc(4096);
  int* scol   = (int*)alloc((size_t)E * 4);
  __bf16* qb      = (__bf16*)alloc((size_t)N * 128 * 2);
  float*  beta    = (float*)alloc((size_t)N * 4);
  float*  W1      = (float*)alloc((size_t)N * 4);
  __bf16* nodebuf = (__bf16*)alloc((size_t)N * 512 * 2);
  __bf16* Wt      = (__bf16*)alloc((size_t)640 * 128 * 2);
  __bf16* aggv16  = (__bf16*)alloc((size_t)N * 384 * 2);
  __bf16* gb      = (__bf16*)alloc((size_t)N * 128 * 2);
  float*  bM      = (float*)alloc(512);
  float*  m2      = (float*)alloc(512);
  float*  c0      = (float*)alloc(256);

  float* s_out = (float*)d_out;
  float* vout  = (float*)d_out + (size_t)N * 128;

  // prep: hist + W transpose + M^T + m2/c0
  hipMemsetAsync(cursor, 0, (size_t)N * 4, stream);
  int nbh = (E + 255) / 256;
  prep_kernel<<<nbh + 256 + 128 + 1, 256, 0, stream>>>(row, cursor, E, Wq, Wkv, Wvec, bq, bkv,
                                                       Wt, bM, m2, c0, nbh);
  int nb = (N + 1023) / 1024;
  scan1_kernel<<<nb, 1024, 0, stream>>>(cursor, off, bsum, N);
  scan3_kernel<<<nb, 1024, 0, stream>>>(bsum, off, cursor, N, E);

  // scatter + gemm1 (merged; gemm1 blocks first)
  int nb1 = (N + 63) / 64;
  int ngemm = 2 * nb1;
  int nbs = (E + 255) / 256;
  scatter_gemm1<<<ngemm + nbs, 256, 0, stream>>>(row, col, cursor, scol, E, ngemm,
                                                 s, Wt, bM, bkv, m2, c0, v,
                                                 qb, beta, nodebuf, N);

  // edge aggregation
  agg_kernel<<<(N + 3) / 4, 256, 0, stream>>>(off, scol, qb, beta, (const char*)nodebuf,
                                              gb, W1, aggv16, N);

  // fused output GEMMs
  int nb2 = (3 * N + 63) / 64;
  gemm23_mfma<<<nb1 + nb2, 256, 0, stream>>>(Wt, bkv, bvec, s, v, gb, W1, aggv16,
                                             s_out, vout, N, nb1);
}